// Round 5
// baseline (28406.470 us; speedup 1.0000x reference)
//
#include <hip/hip_runtime.h>

typedef unsigned short u16;
typedef unsigned int   u32;
typedef unsigned long long u64;

#define Bb   32
#define Tt   256
#define Ss   512
#define Hh   512
#define G4H  2048
#define NBLK 256

// ---- dtype-polymorphic load/store: F32 ? fp32 : bf16 ------------------------
template<bool F32>
__device__ __forceinline__ float ldin(const void* p, size_t i) {
    if constexpr (F32) {
        return ((const float*)p)[i];
    } else {
        u32 v = ((u32)((const u16*)p)[i]) << 16;
        return __uint_as_float(v);
    }
}
template<bool F32>
__device__ __forceinline__ void stout(void* p, size_t i, float f) {
    if constexpr (F32) {
        ((float*)p)[i] = f;
    } else {
        u32 x = __float_as_uint(f);
        u32 r = x + 0x7fffu + ((x >> 16) & 1u);   // RNE
        ((u16*)p)[i] = (u16)(r >> 16);
    }
}
template<bool F32>
__device__ __forceinline__ float4 ld4(const void* p, size_t i) {
    if constexpr (F32) {
        return *(const float4*)((const float*)p + i);
    } else {
        ushort4 u = *(const ushort4*)((const u16*)p + i);
        float4 f;
        f.x = __uint_as_float((u32)u.x << 16);
        f.y = __uint_as_float((u32)u.y << 16);
        f.z = __uint_as_float((u32)u.z << 16);
        f.w = __uint_as_float((u32)u.w << 16);
        return f;
    }
}
__device__ __forceinline__ u32 pack2bf(float a, float b) {
    u32 xa = __float_as_uint(a), xb = __float_as_uint(b);
    u32 ra = (xa + 0x7fffu + ((xa >> 16) & 1u)) >> 16;
    u32 rb = (xb + 0x7fffu + ((xb >> 16) & 1u)) & 0xffff0000u;
    return ra | rb;
}
__device__ __forceinline__ float bflo(u32 u) { return __uint_as_float(u << 16); }
__device__ __forceinline__ float bfhi(u32 u) { return __uint_as_float(u & 0xffff0000u); }

// ---- cache-bypassing (coherence-point) accessors for mutable ws state -------
__device__ __forceinline__ float ldb(const float* p) {
    return __hip_atomic_load(p, __ATOMIC_RELAXED, __HIP_MEMORY_SCOPE_AGENT);
}
__device__ __forceinline__ void stb(float* p, float v) {
    __hip_atomic_store(p, v, __ATOMIC_RELAXED, __HIP_MEMORY_SCOPE_AGENT);
}
__device__ __forceinline__ float2 ldb2(const float* p) {
    u64 v = __hip_atomic_load((const u64*)p, __ATOMIC_RELAXED, __HIP_MEMORY_SCOPE_AGENT);
    float2 r;
    r.x = __uint_as_float((u32)v);
    r.y = __uint_as_float((u32)(v >> 32));
    return r;
}
__device__ __forceinline__ u32 ldbu(const u32* p) {
    return __hip_atomic_load(p, __ATOMIC_RELAXED, __HIP_MEMORY_SCOPE_AGENT);
}
__device__ __forceinline__ void stbu(u32* p, u32 v) {
    __hip_atomic_store(p, v, __ATOMIC_RELAXED, __HIP_MEMORY_SCOPE_AGENT);
}

// ---- 2-level tree barrier: 16 leaves x 16 blocks + root, relaxed atomics ----
__device__ __forceinline__ void gbar2(int* bars, int expected) {
    __syncthreads();
    if (threadIdx.x == 0) {
        const int leaf = blockIdx.x >> 4;
        int* lc = bars + leaf * 32;
        int* lg = bars + (16 + leaf) * 32;
        int* rc = bars + 32 * 32;
        int* rg = bars + 33 * 32;
        if (__hip_atomic_fetch_add(lc, 1, __ATOMIC_RELAXED, __HIP_MEMORY_SCOPE_AGENT) == 15) {
            asm volatile("s_waitcnt vmcnt(0)" ::: "memory");
            if (__hip_atomic_fetch_add(rc, 1, __ATOMIC_RELAXED, __HIP_MEMORY_SCOPE_AGENT) == 15) {
                __hip_atomic_store(rc, 0, __ATOMIC_RELAXED, __HIP_MEMORY_SCOPE_AGENT);
                asm volatile("s_waitcnt vmcnt(0)" ::: "memory");
                __hip_atomic_store(rg, expected, __ATOMIC_RELAXED, __HIP_MEMORY_SCOPE_AGENT);
            } else {
                while (__hip_atomic_load(rg, __ATOMIC_RELAXED, __HIP_MEMORY_SCOPE_AGENT) < expected)
                    __builtin_amdgcn_s_sleep(1);
            }
            __hip_atomic_store(lc, 0, __ATOMIC_RELAXED, __HIP_MEMORY_SCOPE_AGENT);
            asm volatile("s_waitcnt vmcnt(0)" ::: "memory");
            __hip_atomic_store(lg, expected, __ATOMIC_RELAXED, __HIP_MEMORY_SCOPE_AGENT);
        } else {
            while (__hip_atomic_load(lg, __ATOMIC_RELAXED, __HIP_MEMORY_SCOPE_AGENT) < expected)
                __builtin_amdgcn_s_sleep(1);
        }
    }
    __syncthreads();
}

// ---------------------------------------------------------------------------
// K0: dtype detector + barrier-state init
// ---------------------------------------------------------------------------
__global__ __launch_bounds__(256) void k_detect(const void* ctx, int* flag, int* bars) {
    __shared__ int c_sh;
    if (threadIdx.x == 0) c_sh = 0;
    __syncthreads();
    const u16* p = (const u16*)ctx;
    int c = 0;
    for (int i = threadIdx.x; i < 16384; i += 256) {
        int e = (p[i] >> 7) & 0xFF;
        if (e >= 0xC8) c++;
    }
    atomicAdd(&c_sh, c);
    __syncthreads();
    if (threadIdx.x == 0) *flag = (c_sh > 64) ? 1 : 0;
    if (threadIdx.x < 34) bars[threadIdx.x * 32] = 0;
}

// ---------------------------------------------------------------------------
// K0b: generic -> bf16 conversion (copy-through if already bf16).
// grid covers count/2048; each thread 8 elems.
// ---------------------------------------------------------------------------
__global__ __launch_bounds__(256) void k_cvt(const int* flag, const void* src, u16* dst) {
    const size_t i = ((size_t)blockIdx.x * 256 + threadIdx.x) * 8;
    if (*flag) {
        const float* s = (const float*)src + i;
        float4 v0 = *(const float4*)(s);
        float4 v1 = *(const float4*)(s + 4);
        uint4 o;
        o.x = pack2bf(v0.x, v0.y);
        o.y = pack2bf(v0.z, v0.w);
        o.z = pack2bf(v1.x, v1.y);
        o.w = pack2bf(v1.z, v1.w);
        *(uint4*)(dst + i) = o;
    } else {
        *(uint4*)(dst + i) = *(const uint4*)((const u16*)src + i);
    }
}

// ===========================================================================
// Fused persistent kernel: 256 blocks x 512 threads
//  - ctx slice resident in LDS (bf16-packed, skewed) for the whole run
//  - weights bf16 in workspace (L2-resident: ~1.4 MB/XCD both layers)
//  - state exchange (h/hy/tgt) bf16-packed u32 bypass; wc fp32 atomic
// ===========================================================================
struct KP {
    const void *input, *h0, *c0, *ctx, *bi, *bhp;
    const u16 *wiB, *whB, *waiB, *waoB;
    void* out;
    const int* flag;
    int* bars;
    u32 *hB, *hyB, *tgtB;
    float *wc_ws, *e_ws, *esum_ws;
};

#define CTXU_FLOATS 16896
#define SCR_FLOATS  10544
#define SMEM_FLOATS (CTXU_FLOATS + SCR_FLOATS + 64)

template<bool F32>
__device__ void run_all(const KP& p, float* smem) {
    const int bid = blockIdx.x;
    const int tid = threadIdx.x;
    const size_t XN = (size_t)Bb * Tt * Hh;
    const size_t HN = (size_t)Bb * Hh;
    u32*   ctxU = (u32*)smem;
    float* S    = smem + CTXU_FLOATS;
    float* cL   = smem + CTXU_FLOATS + SCR_FLOATS;
    int ep = 0;

    // ---- one-time: stage this block's ctx slice into LDS (bf16-packed, skewed)
    {
        const int b = bid >> 3, sg = bid & 7;
        for (int idx = tid; idx < 8192; idx += 512) {
            const int r = idx >> 7, q4 = (idx & 127) << 2;
            float4 v = ld4<F32>(p.ctx, ((size_t)((sg << 6) + r) * Bb + b) * Hh + q4);
            const int w = q4 >> 1;
            const int sk = w >> 5;
            ctxU[r * 264 + w + sk]     = pack2bf(v.x, v.y);
            ctxU[r * 264 + w + 1 + sk] = pack2bf(v.z, v.w);
        }
    }
    __syncthreads();

    for (int l = 0; l < 2; ++l) {
        const void* xsrc = (l == 0) ? p.input : (const void*)p.out;
        const size_t wOffG  = (size_t)l * Hh * G4H;
        const size_t bOffG  = (size_t)l * G4H;
        const size_t wOffAi = (size_t)l * Hh * Hh;
        const size_t wOffAo = (size_t)l * 2 * Hh * Hh;
        const size_t offH1  = XN + (size_t)l * HN;
        const size_t offC1  = XN + 2 * HN + (size_t)l * HN;
        const size_t offAtt = XN + 4 * HN;
        const int writeAtt = l;

        for (int t = 0; t < Tt; ++t) {
            const int last = (t == Tt - 1);

            { // ---- P1: gates -> hy, cy.  blocks = (bq 4: 8 b's) x (colg 64: 8 n) ----
                const int bq = bid >> 6, colg = bid & 63;
                const int b0 = bq << 3;
                float* xh  = S;                 // [8][1025]
                float* red = S + 8200;          // [4][520]
                float* ga  = S + 10280;         // [8][33]
                for (int idx = tid; idx < 1024; idx += 512) {
                    const int bb = idx >> 7, q = (idx & 127) << 2;
                    float4 v = ld4<F32>(xsrc, ((size_t)(b0 + bb) * Tt + t) * Hh + q);
                    float* d = xh + bb * 1025 + q;
                    d[0] = v.x; d[1] = v.y; d[2] = v.z; d[3] = v.w;
                }
                if (t == 0) {
                    for (int idx = tid; idx < 1024; idx += 512) {
                        const int bb = idx >> 7, q = (idx & 127) << 2;
                        float4 v = ld4<F32>(p.h0, (size_t)(b0 + bb) * Hh + q);
                        float* d = xh + bb * 1025 + 512 + q;
                        d[0] = v.x; d[1] = v.y; d[2] = v.z; d[3] = v.w;
                    }
                } else {
                    for (int idx = tid; idx < 2048; idx += 512) {
                        const int bb = idx >> 8, pr = idx & 255;
                        u32 u = ldbu(p.hB + (size_t)(b0 + bb) * 256 + pr);
                        float* d = xh + bb * 1025 + 512 + (pr << 1);
                        d[0] = bflo(u); d[1] = bfhi(u);
                    }
                }
                __syncthreads();
                const int kq = tid >> 6, cq = (tid >> 3) & 7, b8 = tid & 7;
                const int gq = cq >> 1, j4 = (cq & 1) << 2;
                const int col = (gq << 9) + (colg << 3) + j4;
                const u16* Wb = (kq < 4) ? p.wiB : p.whB;
                size_t wi = wOffG + ((size_t)((kq & 3) << 7)) * G4H + col;
                const float* xr = xh + b8 * 1025 + (kq << 7);
                float a0 = 0.f, a1 = 0.f, a2 = 0.f, a3 = 0.f;
                #pragma unroll 16
                for (int k = 0; k < 128; ++k) {
                    float4 w = ld4<false>(Wb, wi);
                    float xv = xr[k];
                    a0 += xv * w.x; a1 += xv * w.y; a2 += xv * w.z; a3 += xv * w.w;
                    wi += G4H;
                }
                red[0 * 520 + tid] = a0; red[1 * 520 + tid] = a1;
                red[2 * 520 + tid] = a2; red[3 * 520 + tid] = a3;
                __syncthreads();
                if (tid < 256) {
                    const int rb8 = tid >> 5, cl = tid & 31;
                    const int rcq = cl >> 2, rc = cl & 3;
                    float s = 0.f;
                    #pragma unroll
                    for (int q = 0; q < 8; ++q) s += red[rc * 520 + (q << 6) + (rcq << 3) + rb8];
                    ga[rb8 * 33 + cl] = s;
                }
                __syncthreads();
                if (tid < 32) {
                    const int b8i = tid >> 2, pp = tid & 3;
                    const int b = b0 + b8i;
                    float hv[2];
                    #pragma unroll
                    for (int e = 0; e < 2; ++e) {
                        const int nn = (pp << 1) + e;
                        const int n = (colg << 3) + nn;
                        const int gb = b8i * 33 + nn;
                        float gi = ga[gb]      + ldin<F32>(p.bi, bOffG + n)        + ldin<F32>(p.bhp, bOffG + n);
                        float gf = ga[gb + 8]  + ldin<F32>(p.bi, bOffG + 512 + n)  + ldin<F32>(p.bhp, bOffG + 512 + n);
                        float gg = ga[gb + 16] + ldin<F32>(p.bi, bOffG + 1024 + n) + ldin<F32>(p.bhp, bOffG + 1024 + n);
                        float go = ga[gb + 24] + ldin<F32>(p.bi, bOffG + 1536 + n) + ldin<F32>(p.bhp, bOffG + 1536 + n);
                        float ig = 1.f / (1.f + __expf(-gi));
                        float fg = 1.f / (1.f + __expf(-gf));
                        float g2 = tanhf(gg);
                        float og = 1.f / (1.f + __expf(-go));
                        const int ci = (b8i << 3) + nn;
                        float cp = (t == 0) ? ldin<F32>(p.c0, (size_t)b * Hh + n) : cL[ci];
                        float cy = fg * cp + ig * g2;
                        hv[e] = og * tanhf(cy);
                        cL[ci] = cy;
                        if (last) stout<F32>(p.out, offC1 + (size_t)b * Hh + n, cy);
                    }
                    stbu(p.hyB + (size_t)b * 256 + (colg << 2) + pp, pack2bf(hv[0], hv[1]));
                }
            }
            ++ep; gbar2(p.bars, ep);

            { // ---- P2: tgt = hy @ Wa_in. blocks = (bq 4) x (colg 64: 8 cols) ----
                const int bq = bid >> 6, colg = bid & 63;
                const int b0 = bq << 3;
                float* hyL = S;                 // [8][513]
                float* red = S + 4104;          // [4][520]
                for (int idx = tid; idx < 2048; idx += 512) {
                    const int bb = idx >> 8, pr = idx & 255;
                    u32 u = ldbu(p.hyB + (size_t)(b0 + bb) * 256 + pr);
                    hyL[bb * 513 + (pr << 1)]     = bflo(u);
                    hyL[bb * 513 + (pr << 1) + 1] = bfhi(u);
                }
                if (colg == 0) {
                    for (int idx = tid; idx < 4096; idx += 512)
                        stb(p.wc_ws + (size_t)(b0 + (idx >> 9)) * Hh + (idx & 511), 0.f);
                    if (tid < 8) stb(p.esum_ws + b0 + tid, 0.f);
                }
                __syncthreads();
                const int kq = tid >> 4, cq = (tid >> 3) & 1, b8 = tid & 7;
                const int col = (colg << 3) + (cq << 2);
                size_t wi = wOffAi + ((size_t)(kq << 4)) * Hh + col;
                const float* hr = hyL + b8 * 513 + (kq << 4);
                float a0 = 0.f, a1 = 0.f, a2 = 0.f, a3 = 0.f;
                #pragma unroll
                for (int k = 0; k < 16; ++k) {
                    float4 w = ld4<false>(p.waiB, wi);
                    float xv = hr[k];
                    a0 += xv * w.x; a1 += xv * w.y; a2 += xv * w.z; a3 += xv * w.w;
                    wi += Hh;
                }
                red[0 * 520 + tid] = a0; red[1 * 520 + tid] = a1;
                red[2 * 520 + tid] = a2; red[3 * 520 + tid] = a3;
                __syncthreads();
                if (tid < 32) {
                    const int b8i = tid >> 2, pp = tid & 3;
                    float tv[2];
                    #pragma unroll
                    for (int e = 0; e < 2; ++e) {
                        const int cl = (pp << 1) + e;
                        const int rcq = cl >> 2, rc = cl & 3;
                        float s = 0.f;
                        #pragma unroll
                        for (int q = 0; q < 32; ++q) s += red[rc * 520 + (q << 4) + (rcq << 3) + b8i];
                        tv[e] = s;
                    }
                    stbu(p.tgtB + (size_t)(b0 + b8i) * 256 + (colg << 2) + pp, pack2bf(tv[0], tv[1]));
                }
            }
            ++ep; gbar2(p.bars, ep);

            { // ---- P3: scores + exp + wc partials, ctx from LDS. blocks = (b 32) x (sg 8) ----
                const int b = bid >> 3, sg = bid & 7;
                float* tgtL = S;                // 512
                float* eL   = S + 512;          // 64
                if (tid < 256) {
                    u32 u = ldbu(p.tgtB + (size_t)b * 256 + tid);
                    tgtL[tid << 1]       = bflo(u);
                    tgtL[(tid << 1) + 1] = bfhi(u);
                }
                __syncthreads();
                const int r = tid >> 3, kq = tid & 7;
                const u32* cw = ctxU + r * 264 + kq * 33;
                const float* tp = tgtL + (kq << 6);
                float d = 0.f;
                #pragma unroll 8
                for (int j = 0; j < 32; ++j) {
                    u32 u = cw[j];
                    d += __uint_as_float(u << 16)         * tp[2 * j]
                       + __uint_as_float(u & 0xffff0000u) * tp[2 * j + 1];
                }
                d += __shfl_xor(d, 1); d += __shfl_xor(d, 2); d += __shfl_xor(d, 4);
                if (kq == 0) {
                    float e = __expf(d);        // bounded: |score| <~ 60, safe in fp32
                    eL[r] = e;
                    stb(p.e_ws + (size_t)b * Ss + (sg << 6) + r, e);
                }
                __syncthreads();
                if (tid < 64) {
                    float w = eL[tid];
                    #pragma unroll
                    for (int o = 32; o > 0; o >>= 1) w += __shfl_xor(w, o);
                    if (tid == 0) atomicAdd(p.esum_ws + b, w);
                }
                const int wd = tid >> 1, hodd = tid & 1;
                const int woff = wd + (wd >> 5);
                float acc = 0.f;
                #pragma unroll 8
                for (int rr = 0; rr < 64; ++rr) {
                    u32 u = ctxU[rr * 264 + woff];
                    float v = hodd ? __uint_as_float(u & 0xffff0000u) : __uint_as_float(u << 16);
                    acc += eL[rr] * v;
                }
                atomicAdd(p.wc_ws + (size_t)b * Hh + tid, acc);
            }
            ++ep; gbar2(p.bars, ep);

            { // ---- P4: h~ = tanh([wc,hy]@Wa_out). blocks = (bq 4) x (colg 64: 8 cols) ----
                const int bq = bid >> 6, colg = bid & 63;
                const int b0 = bq << 3;
                float* vL   = S;                // [8][1025]
                float* red  = S + 8200;         // [4][520]
                float* invL = S + 10280;        // [8]
                if (tid < 8) invL[tid] = 1.f / ldb(p.esum_ws + b0 + tid);
                __syncthreads();
                for (int idx = tid; idx < 2048; idx += 512) {
                    const int bb = idx >> 8, q = (idx & 255) << 1;
                    float2 v = ldb2(p.wc_ws + (size_t)(b0 + bb) * Hh + q);
                    const float iv = invL[bb];
                    vL[bb * 1025 + q] = v.x * iv; vL[bb * 1025 + q + 1] = v.y * iv;
                }
                for (int idx = tid; idx < 2048; idx += 512) {
                    const int bb = idx >> 8, pr = idx & 255;
                    u32 u = ldbu(p.hyB + (size_t)(b0 + bb) * 256 + pr);
                    vL[bb * 1025 + 512 + (pr << 1)]     = bflo(u);
                    vL[bb * 1025 + 512 + (pr << 1) + 1] = bfhi(u);
                }
                __syncthreads();
                const int kq = tid >> 4, cq = (tid >> 3) & 1, b8 = tid & 7;
                const int col = (colg << 3) + (cq << 2);
                size_t wi = wOffAo + ((size_t)(kq << 5)) * Hh + col;
                const float* vr = vL + b8 * 1025 + (kq << 5);
                float a0 = 0.f, a1 = 0.f, a2 = 0.f, a3 = 0.f;
                #pragma unroll 8
                for (int k = 0; k < 32; ++k) {
                    float4 w = ld4<false>(p.waoB, wi);
                    float xv = vr[k];
                    a0 += xv * w.x; a1 += xv * w.y; a2 += xv * w.z; a3 += xv * w.w;
                    wi += Hh;
                }
                red[0 * 520 + tid] = a0; red[1 * 520 + tid] = a1;
                red[2 * 520 + tid] = a2; red[3 * 520 + tid] = a3;
                __syncthreads();
                if (tid < 32) {
                    const int b8i = tid >> 2, pp = tid & 3;
                    const int b = b0 + b8i;
                    float hv[2];
                    #pragma unroll
                    for (int e = 0; e < 2; ++e) {
                        const int cl = (pp << 1) + e;
                        const int rcq = cl >> 2, rc = cl & 3;
                        float s = 0.f;
                        #pragma unroll
                        for (int q = 0; q < 32; ++q) s += red[rc * 520 + (q << 4) + (rcq << 3) + b8i];
                        float th = tanhf(s);
                        const int n2 = (colg << 3) + cl;
                        hv[e] = th;
                        stout<F32>(p.out, ((size_t)b * Tt + t) * Hh + n2, th);
                        if (last) stout<F32>(p.out, offH1 + (size_t)b * Hh + n2, th);
                    }
                    stbu(p.hB + (size_t)b * 256 + (colg << 2) + pp, pack2bf(hv[0], hv[1]));
                }
                if (writeAtt && colg < 8) {
                    const int b8a = tid >> 6, si = tid & 63;
                    const int s = (colg << 6) + si;
                    float pv = ldb(p.e_ws + (size_t)(b0 + b8a) * Ss + s) * invL[b8a];
                    stout<F32>(p.out, offAtt + (size_t)s * (Tt * Bb) + (size_t)t * Bb + (b0 + b8a), pv);
                }
            }
            ++ep; gbar2(p.bars, ep);
        }

        if (l == 0) {
            // heavy fence: flush dirty x rows (normal stores) across XCDs
            __threadfence();
            ++ep; gbar2(p.bars, ep);
            __threadfence();
        }
    }
}

__global__ __launch_bounds__(512, 2) void kmain(KP p) {
    __shared__ float smem[SMEM_FLOATS];
    if (*p.flag) run_all<true >(p, smem);
    else         run_all<false>(p, smem);
}

// ===========================================================================
// Fallback path: original per-timestep kernels (proven correct)
// ===========================================================================
template<bool F32>
__device__ __forceinline__ void gates_body(
    const void* xsrc, const void* h0, const void* c0,
    const void* Wi, const void* bi, const void* Wh, const void* bh,
    size_t wOff, size_t bOff,
    const float* h_ws, float* c_ws, float* hy_ws,
    void* out, unsigned long long offC1, int t, int writeC1)
{
    __shared__ float xh[1024];
    __shared__ float red[4][32][8];
    __shared__ float ga[4][32];

    const int b  = blockIdx.x >> 4;
    const int jc = blockIdx.x & 15;
    const int tid = threadIdx.x;

    const size_t xrow = ((size_t)b * Tt + t) * Hh;
    for (int i = tid; i < 512; i += 256) xh[i] = ldin<F32>(xsrc, xrow + i);
    if (t == 0) {
        for (int i = tid; i < 512; i += 256) xh[512 + i] = ldin<F32>(h0, (size_t)b * Hh + i);
    } else {
        for (int i = tid; i < 512; i += 256) xh[512 + i] = h_ws[b * Hh + i];
    }
    __syncthreads();

    const int jl = tid & 31;
    const int kq = tid >> 5;
    const int j  = jc * 32 + jl;
    const void* Wbase = (kq < 4) ? Wi : Wh;
    const int k0 = (kq & 3) * 128;
    const int xoff = (kq < 4) ? 0 : 512;

    float a0 = 0.f, a1 = 0.f, a2 = 0.f, a3 = 0.f;
    size_t widx = wOff + (size_t)k0 * G4H + j;
    #pragma unroll 4
    for (int k = 0; k < 128; ++k) {
        float xv = xh[xoff + k0 + k];
        a0 += xv * ldin<F32>(Wbase, widx + 0 * Hh);
        a1 += xv * ldin<F32>(Wbase, widx + 1 * Hh);
        a2 += xv * ldin<F32>(Wbase, widx + 2 * Hh);
        a3 += xv * ldin<F32>(Wbase, widx + 3 * Hh);
        widx += G4H;
    }
    red[0][jl][kq] = a0; red[1][jl][kq] = a1;
    red[2][jl][kq] = a2; red[3][jl][kq] = a3;
    __syncthreads();

    if (tid < 128) {
        int g = tid >> 5, jj = tid & 31;
        float s = 0.f;
        #pragma unroll
        for (int q = 0; q < 8; ++q) s += red[g][jj][q];
        ga[g][jj] = s;
    }
    __syncthreads();

    if (tid < 32) {
        int jj = tid;
        int n = jc * 32 + jj;
        float gi = ga[0][jj] + ldin<F32>(bi, bOff + 0 * Hh + n) + ldin<F32>(bh, bOff + 0 * Hh + n);
        float gf = ga[1][jj] + ldin<F32>(bi, bOff + 1 * Hh + n) + ldin<F32>(bh, bOff + 1 * Hh + n);
        float gg = ga[2][jj] + ldin<F32>(bi, bOff + 2 * Hh + n) + ldin<F32>(bh, bOff + 2 * Hh + n);
        float go = ga[3][jj] + ldin<F32>(bi, bOff + 3 * Hh + n) + ldin<F32>(bh, bOff + 3 * Hh + n);
        float ig = 1.f / (1.f + __expf(-gi));
        float fg = 1.f / (1.f + __expf(-gf));
        float g2 = tanhf(gg);
        float og = 1.f / (1.f + __expf(-go));
        float cp = (t == 0) ? ldin<F32>(c0, (size_t)b * Hh + n) : c_ws[b * Hh + n];
        float cy = fg * cp + ig * g2;
        float hy = og * tanhf(cy);
        c_ws[b * Hh + n]  = cy;
        hy_ws[b * Hh + n] = hy;
        if (writeC1) stout<F32>(out, offC1 + (size_t)b * Hh + n, cy);
    }
}

__global__ __launch_bounds__(256) void k_gates(
    const int* flag, const void* xsrc, const void* h0, const void* c0,
    const void* Wi, const void* bi, const void* Wh, const void* bh,
    unsigned long long wOff, unsigned long long bOff,
    const float* h_ws, float* c_ws, float* hy_ws,
    void* out, unsigned long long offC1, int t, int writeC1)
{
    if (*flag) gates_body<true >(xsrc, h0, c0, Wi, bi, Wh, bh, wOff, bOff, h_ws, c_ws, hy_ws, out, offC1, t, writeC1);
    else       gates_body<false>(xsrc, h0, c0, Wi, bi, Wh, bh, wOff, bOff, h_ws, c_ws, hy_ws, out, offC1, t, writeC1);
}

template<bool F32>
__device__ __forceinline__ void target_body(
    const float* hy_ws, const void* Wa_in, size_t wOff, float* tgt_ws)
{
    __shared__ float hyL[512];
    __shared__ float red[64][4];

    const int b  = blockIdx.x >> 3;
    const int nc = blockIdx.x & 7;
    const int tid = threadIdx.x;

    for (int i = tid; i < 512; i += 256) hyL[i] = hy_ws[b * Hh + i];
    __syncthreads();

    const int nl = tid & 63;
    const int kq = tid >> 6;
    const int n  = nc * 64 + nl;
    const int kb = kq * 128;
    float acc = 0.f;
    #pragma unroll 4
    for (int k = 0; k < 128; ++k)
        acc += hyL[kb + k] * ldin<F32>(Wa_in, wOff + (size_t)(kb + k) * Hh + n);
    red[nl][kq] = acc;
    __syncthreads();

    if (tid < 64) {
        float s = red[tid][0] + red[tid][1] + red[tid][2] + red[tid][3];
        tgt_ws[b * Hh + nc * 64 + tid] = s;
    }
}

__global__ __launch_bounds__(256) void k_target(
    const int* flag, const float* hy_ws, const void* Wa_in,
    unsigned long long wOff, float* tgt_ws)
{
    if (*flag) target_body<true >(hy_ws, Wa_in, wOff, tgt_ws);
    else       target_body<false>(hy_ws, Wa_in, wOff, tgt_ws);
}

template<bool F32>
__device__ __forceinline__ void scores_body(
    const void* ctx, const float* tgt_ws, float* sc_ws)
{
    const int w    = threadIdx.x >> 6;
    const int lane = threadIdx.x & 63;
    const int id = blockIdx.x * 4 + w;
    const int b = id & 31;
    const int s = id >> 5;

    const size_t base = ((size_t)s * Bb + b) * Hh + lane * 8;
    const float* tp = tgt_ws + (size_t)b * Hh + lane * 8;
    float d = 0.f;
    #pragma unroll
    for (int i = 0; i < 8; ++i) d += ldin<F32>(ctx, base + i) * tp[i];
    #pragma unroll
    for (int o = 32; o > 0; o >>= 1) d += __shfl_xor(d, o);
    if (lane == 0) sc_ws[b * Ss + s] = d;
}

__global__ __launch_bounds__(256) void k_scores(
    const int* flag, const void* ctx, const float* tgt_ws, float* sc_ws)
{
    if (*flag) scores_body<true >(ctx, tgt_ws, sc_ws);
    else       scores_body<false>(ctx, tgt_ws, sc_ws);
}

template<bool F32>
__device__ __forceinline__ void wc_body(
    const void* ctx, const float* sc_ws, float* wc_ws,
    void* out, unsigned long long offAtt, int t, int writeAtt)
{
    __shared__ float scL[512];
    __shared__ float red[256];

    const int b   = blockIdx.x >> 2;
    const int hc  = blockIdx.x & 3;
    const int tid = threadIdx.x;

    scL[tid]       = sc_ws[b * Ss + tid];
    scL[tid + 256] = sc_ws[b * Ss + tid + 256];
    __syncthreads();

    red[tid] = fmaxf(scL[tid], scL[tid + 256]);
    __syncthreads();
    for (int o = 128; o > 0; o >>= 1) {
        if (tid < o) red[tid] = fmaxf(red[tid], red[tid + o]);
        __syncthreads();
    }
    const float M = red[0];
    __syncthreads();

    red[tid] = __expf(scL[tid] - M) + __expf(scL[tid + 256] - M);
    __syncthreads();
    for (int o = 128; o > 0; o >>= 1) {
        if (tid < o) red[tid] += red[tid + o];
        __syncthreads();
    }
    const float inv = 1.f / red[0];
    __syncthreads();

    const int h    = hc * 128 + (tid & 127);
    const int half = tid >> 7;
    float acc = 0.f;
    const int s0 = half * 256;
    for (int s = s0; s < s0 + 256; ++s)
        acc += __expf(scL[s] - M) * ldin<F32>(ctx, ((size_t)s * Bb + b) * Hh + h);

    red[tid] = acc;
    __syncthreads();
    if (half == 0)
        wc_ws[b * Hh + h] = (red[tid] + red[tid + 128]) * inv;

    if (writeAtt && hc == 0) {
        float p0 = __expf(scL[tid] - M) * inv;
        float p1 = __expf(scL[tid + 256] - M) * inv;
        stout<F32>(out, offAtt + (size_t)tid         * (Tt * Bb) + (size_t)t * Bb + b, p0);
        stout<F32>(out, offAtt + (size_t)(tid + 256) * (Tt * Bb) + (size_t)t * Bb + b, p1);
    }
}

__global__ __launch_bounds__(256) void k_wc(
    const int* flag, const void* ctx, const float* sc_ws, float* wc_ws,
    void* out, unsigned long long offAtt, int t, int writeAtt)
{
    if (*flag) wc_body<true >(ctx, sc_ws, wc_ws, out, offAtt, t, writeAtt);
    else       wc_body<false>(ctx, sc_ws, wc_ws, out, offAtt, t, writeAtt);
}

template<bool F32>
__device__ __forceinline__ void out_body(
    const float* hy_ws, const float* wc_ws, const void* Wa_out, size_t wOff,
    float* h_ws, void* out, unsigned long long offH1, int t, int writeH1)
{
    __shared__ float vL[1024];
    __shared__ float red[32][8];

    const int b  = blockIdx.x >> 4;
    const int nc = blockIdx.x & 15;
    const int tid = threadIdx.x;

    for (int h = tid; h < 512; h += 256) {
        vL[h]       = wc_ws[b * Hh + h];
        vL[512 + h] = hy_ws[b * Hh + h];
    }
    __syncthreads();

    const int nl = tid & 31;
    const int kq = tid >> 5;
    const int n  = nc * 32 + nl;
    const int kb = kq * 128;
    float acc = 0.f;
    #pragma unroll 4
    for (int k = 0; k < 128; ++k)
        acc += vL[kb + k] * ldin<F32>(Wa_out, wOff + (size_t)(kb + k) * Hh + n);
    red[nl][kq] = acc;
    __syncthreads();

    if (tid < 32) {
        float s = 0.f;
        #pragma unroll
        for (int q = 0; q < 8; ++q) s += red[tid][q];
        float th = tanhf(s);
        int n2 = nc * 32 + tid;
        h_ws[b * Hh + n2] = th;
        stout<F32>(out, ((size_t)b * Tt + t) * Hh + n2, th);
        if (writeH1) stout<F32>(out, offH1 + (size_t)b * Hh + n2, th);
    }
}

__global__ __launch_bounds__(256) void k_out(
    const int* flag, const float* hy_ws, const float* wc_ws, const void* Wa_out,
    unsigned long long wOff, float* h_ws, void* out,
    unsigned long long offH1, int t, int writeH1)
{
    if (*flag) out_body<true >(hy_ws, wc_ws, Wa_out, wOff, h_ws, out, offH1, t, writeH1);
    else       out_body<false>(hy_ws, wc_ws, Wa_out, wOff, h_ws, out, offH1, t, writeH1);
}

// ---------------------------------------------------------------------------
extern "C" void kernel_launch(void* const* d_in, const int* in_sizes, int n_in,
                              void* d_out, int out_size, void* d_ws, size_t ws_size,
                              hipStream_t stream)
{
    const void* input  = d_in[0];
    const void* h0     = d_in[1];
    const void* c0     = d_in[2];
    const void* ctx    = d_in[3];
    const void* Wi     = d_in[4];
    const void* bi     = d_in[5];
    const void* Wh     = d_in[6];
    const void* bh     = d_in[7];
    const void* Wa_in  = d_in[8];
    const void* Wa_out = d_in[9];

    const size_t XN = (size_t)Bb * Tt * Hh;
    const size_t HN = (size_t)Bb * Hh;
    const unsigned long long offH1base = XN;
    const unsigned long long offC1base = XN + 2 * HN;
    const unsigned long long offAtt    = XN + 4 * HN;

    char* base = (char*)d_ws;
    int* flag = (int*)base;
    int* bars = (int*)(base + 128);                    // 34 slots x 128 B
    float* f  = (float*)(base + 128 + 34 * 128);
    float* h_ws    = f; f += HN;                       // fallback only
    float* c_ws    = f; f += HN;                       // fallback only
    float* hy_ws   = f; f += HN;                       // fallback only
    float* tgt_ws  = f; f += HN;                       // fallback only
    float* wc_ws   = f; f += HN;
    float* e_ws    = f; f += (size_t)Bb * Ss;
    float* sc_ws   = f; f += (size_t)Bb * Ss;          // fallback only
    float* esum_ws = f; f += 64;

    size_t off = ((size_t)((char*)f - base) + 255) & ~(size_t)255;
    u32* hB   = (u32*)(base + off); off += 32 * 256 * 4;
    u32* hyB  = (u32*)(base + off); off += 32 * 256 * 4;
    u32* tgtB = (u32*)(base + off); off += 32 * 256 * 4;
    off = (off + 255) & ~(size_t)255;
    const size_t NWI  = (size_t)2 * 512 * 2048;        // Wi elems
    const size_t NWH  = (size_t)2 * 512 * 2048;
    const size_t NWAI = (size_t)2 * 512 * 512;
    const size_t NWAO = (size_t)2 * 1024 * 512;
    u16* wiB  = (u16*)(base + off); off += NWI * 2;
    u16* whB  = (u16*)(base + off); off += NWH * 2;
    u16* waiB = (u16*)(base + off); off += NWAI * 2;
    u16* waoB = (u16*)(base + off); off += NWAO * 2;
    const int fits = (ws_size >= off) ? 1 : 0;

    k_detect<<<dim3(1), dim3(256), 0, stream>>>(ctx, flag, bars);

    hipError_t err = hipErrorUnknown;
    if (fits) {
        k_cvt<<<dim3((unsigned)(NWI  / 2048)), dim3(256), 0, stream>>>(flag, Wi,     wiB);
        k_cvt<<<dim3((unsigned)(NWH  / 2048)), dim3(256), 0, stream>>>(flag, Wh,     whB);
        k_cvt<<<dim3((unsigned)(NWAI / 2048)), dim3(256), 0, stream>>>(flag, Wa_in,  waiB);
        k_cvt<<<dim3((unsigned)(NWAO / 2048)), dim3(256), 0, stream>>>(flag, Wa_out, waoB);

        KP hp;
        hp.input = input; hp.h0 = h0; hp.c0 = c0; hp.ctx = ctx;
        hp.bi = bi; hp.bhp = bh;
        hp.wiB = wiB; hp.whB = whB; hp.waiB = waiB; hp.waoB = waoB;
        hp.out = d_out; hp.flag = flag; hp.bars = bars;
        hp.hB = hB; hp.hyB = hyB; hp.tgtB = tgtB;
        hp.wc_ws = wc_ws; hp.e_ws = e_ws; hp.esum_ws = esum_ws;

        void* kargs[] = { &hp };
        err = hipLaunchCooperativeKernel(kmain, dim3(NBLK), dim3(512), kargs, 0u, stream);
    }

    if (err != hipSuccess) {
        (void)hipGetLastError();   // clear error state
        // Fallback: proven per-timestep multi-kernel path
        for (int l = 0; l < 2; ++l) {
            const void* xsrc = (l == 0) ? input : (const void*)d_out;
            const unsigned long long wOffG  = (unsigned long long)l * Hh * G4H;
            const unsigned long long bOffG  = (unsigned long long)l * G4H;
            const unsigned long long wOffAi = (unsigned long long)l * Hh * Hh;
            const unsigned long long wOffAo = (unsigned long long)l * 2 * Hh * Hh;
            const unsigned long long offH1  = offH1base + (unsigned long long)l * HN;
            const unsigned long long offC1  = offC1base + (unsigned long long)l * HN;

            for (int t = 0; t < Tt; ++t) {
                const int last = (t == Tt - 1) ? 1 : 0;
                k_gates<<<dim3(512), dim3(256), 0, stream>>>(
                    flag, xsrc, h0, c0, Wi, bi, Wh, bh, wOffG, bOffG,
                    h_ws, c_ws, hy_ws, d_out, offC1, t, last);
                k_target<<<dim3(256), dim3(256), 0, stream>>>(
                    flag, hy_ws, Wa_in, wOffAi, tgt_ws);
                k_scores<<<dim3(4096), dim3(256), 0, stream>>>(
                    flag, ctx, tgt_ws, sc_ws);
                k_wc<<<dim3(128), dim3(256), 0, stream>>>(
                    flag, ctx, sc_ws, wc_ws, d_out, offAtt, t, l);
                k_out<<<dim3(512), dim3(256), 0, stream>>>(
                    flag, hy_ws, wc_ws, Wa_out, wOffAo, h_ws, d_out, offH1, t, last);
            }
        }
    }
}

// Round 7
// 17230.490 us; speedup vs baseline: 1.6486x; 1.6486x over previous
//
#include <hip/hip_runtime.h>

typedef unsigned short u16;
typedef unsigned int   u32;
typedef unsigned long long u64;

#define Bb   32
#define Tt   256
#define Ss   512
#define Hh   512
#define G4H  2048
#define NBLK 256

// ---- dtype-polymorphic load/store: F32 ? fp32 : bf16 ------------------------
template<bool F32>
__device__ __forceinline__ float ldin(const void* p, size_t i) {
    if constexpr (F32) {
        return ((const float*)p)[i];
    } else {
        u32 v = ((u32)((const u16*)p)[i]) << 16;
        return __uint_as_float(v);
    }
}
template<bool F32>
__device__ __forceinline__ void stout(void* p, size_t i, float f) {
    if constexpr (F32) {
        ((float*)p)[i] = f;
    } else {
        u32 x = __float_as_uint(f);
        u32 r = x + 0x7fffu + ((x >> 16) & 1u);   // RNE
        ((u16*)p)[i] = (u16)(r >> 16);
    }
}
template<bool F32>
__device__ __forceinline__ float4 ld4(const void* p, size_t i) {
    if constexpr (F32) {
        return *(const float4*)((const float*)p + i);
    } else {
        ushort4 u = *(const ushort4*)((const u16*)p + i);
        float4 f;
        f.x = __uint_as_float((u32)u.x << 16);
        f.y = __uint_as_float((u32)u.y << 16);
        f.z = __uint_as_float((u32)u.z << 16);
        f.w = __uint_as_float((u32)u.w << 16);
        return f;
    }
}
__device__ __forceinline__ u32 pack2bf(float a, float b) {
    u32 xa = __float_as_uint(a), xb = __float_as_uint(b);
    u32 ra = (xa + 0x7fffu + ((xa >> 16) & 1u)) >> 16;
    u32 rb = (xb + 0x7fffu + ((xb >> 16) & 1u)) & 0xffff0000u;
    return ra | rb;
}
__device__ __forceinline__ float bflo(u32 u) { return __uint_as_float(u << 16); }
__device__ __forceinline__ float bfhi(u32 u) { return __uint_as_float(u & 0xffff0000u); }

// ---- cache-bypassing (coherence-point) accessors for mutable shared state ---
__device__ __forceinline__ float ldb(const float* p) {
    return __hip_atomic_load(p, __ATOMIC_RELAXED, __HIP_MEMORY_SCOPE_AGENT);
}
__device__ __forceinline__ void stb(float* p, float v) {
    __hip_atomic_store(p, v, __ATOMIC_RELAXED, __HIP_MEMORY_SCOPE_AGENT);
}
__device__ __forceinline__ float2 ldb2(const float* p) {
    u64 v = __hip_atomic_load((const u64*)p, __ATOMIC_RELAXED, __HIP_MEMORY_SCOPE_AGENT);
    float2 r;
    r.x = __uint_as_float((u32)v);
    r.y = __uint_as_float((u32)(v >> 32));
    return r;
}
__device__ __forceinline__ u32 ldbu(const u32* p) {
    return __hip_atomic_load(p, __ATOMIC_RELAXED, __HIP_MEMORY_SCOPE_AGENT);
}
__device__ __forceinline__ void stbu(u32* p, u32 v) {
    __hip_atomic_store(p, v, __ATOMIC_RELAXED, __HIP_MEMORY_SCOPE_AGENT);
}
// bypass pair-store into the output buffer (layer-0 x handoff; no fences needed)
template<bool F32>
__device__ __forceinline__ void stout2b(void* p, size_t i, float a, float b) {
    if constexpr (F32) {
        u64 v = (u64)__float_as_uint(a) | ((u64)__float_as_uint(b) << 32);
        __hip_atomic_store((u64*)((float*)p + i), v, __ATOMIC_RELAXED, __HIP_MEMORY_SCOPE_AGENT);
    } else {
        stbu((u32*)p + (i >> 1), pack2bf(a, b));
    }
}

// ---- 2-level tree grid barrier (HW-proven in R4/R5): 16 leaves x 16 + root --
__device__ __forceinline__ void gbar2(int* bars, int expected) {
    __syncthreads();
    if (threadIdx.x == 0) {
        const int leaf = blockIdx.x >> 4;
        int* lc = bars + leaf * 32;
        int* lg = bars + (16 + leaf) * 32;
        int* rc = bars + 32 * 32;
        int* rg = bars + 33 * 32;
        if (__hip_atomic_fetch_add(lc, 1, __ATOMIC_RELAXED, __HIP_MEMORY_SCOPE_AGENT) == 15) {
            asm volatile("s_waitcnt vmcnt(0)" ::: "memory");
            if (__hip_atomic_fetch_add(rc, 1, __ATOMIC_RELAXED, __HIP_MEMORY_SCOPE_AGENT) == 15) {
                __hip_atomic_store(rc, 0, __ATOMIC_RELAXED, __HIP_MEMORY_SCOPE_AGENT);
                asm volatile("s_waitcnt vmcnt(0)" ::: "memory");
                __hip_atomic_store(rg, expected, __ATOMIC_RELAXED, __HIP_MEMORY_SCOPE_AGENT);
            } else {
                while (__hip_atomic_load(rg, __ATOMIC_RELAXED, __HIP_MEMORY_SCOPE_AGENT) < expected)
                    __builtin_amdgcn_s_sleep(1);
            }
            __hip_atomic_store(lc, 0, __ATOMIC_RELAXED, __HIP_MEMORY_SCOPE_AGENT);
            asm volatile("s_waitcnt vmcnt(0)" ::: "memory");
            __hip_atomic_store(lg, expected, __ATOMIC_RELAXED, __HIP_MEMORY_SCOPE_AGENT);
        } else {
            while (__hip_atomic_load(lg, __ATOMIC_RELAXED, __HIP_MEMORY_SCOPE_AGENT) < expected)
                __builtin_amdgcn_s_sleep(1);
        }
    }
    __syncthreads();
}

// ---------------------------------------------------------------------------
// K0: dtype detector + barrier-state init
// ---------------------------------------------------------------------------
__global__ __launch_bounds__(256) void k_detect(const void* ctx, int* flag, int* bars) {
    __shared__ int c_sh;
    if (threadIdx.x == 0) c_sh = 0;
    __syncthreads();
    const u16* p = (const u16*)ctx;
    int c = 0;
    for (int i = threadIdx.x; i < 16384; i += 256) {
        int e = (p[i] >> 7) & 0xFF;
        if (e >= 0xC8) c++;
    }
    atomicAdd(&c_sh, c);
    __syncthreads();
    if (threadIdx.x == 0) *flag = (c_sh > 64) ? 1 : 0;
    if (threadIdx.x < 34) bars[threadIdx.x * 32] = 0;
}

// ---------------------------------------------------------------------------
// K0b: generic -> bf16 conversion (copy-through if already bf16).
// ---------------------------------------------------------------------------
__global__ __launch_bounds__(256) void k_cvt(const int* flag, const void* src, u16* dst) {
    const size_t i = ((size_t)blockIdx.x * 256 + threadIdx.x) * 8;
    if (*flag) {
        const float* s = (const float*)src + i;
        float4 v0 = *(const float4*)(s);
        float4 v1 = *(const float4*)(s + 4);
        uint4 o;
        o.x = pack2bf(v0.x, v0.y);
        o.y = pack2bf(v0.z, v0.w);
        o.z = pack2bf(v1.x, v1.y);
        o.w = pack2bf(v1.z, v1.w);
        *(uint4*)(dst + i) = o;
    } else {
        *(uint4*)(dst + i) = *(const uint4*)((const u16*)src + i);
    }
}

// ===========================================================================
// Fused persistent kernel: 256 blocks x 512 threads
//  - fixed block identity (b = bid>>3, j = bid&7); XCD = j for all phases
//  - weights bf16, per-XCD slices CONTIGUOUS -> truly L2-resident
//  - 3 phases/ts; HW-proven tree grid barrier
//  - layer-0 x handoff via bypass stores into out (no fences)
// ===========================================================================
struct KP {
    const void *input, *h0, *c0, *ctx, *bi, *bhp;
    const u16 *wiB, *whB, *waiB, *waoB;
    void* out;
    const int* flag;
    int* bars;
    u32 *hB, *hyB;
    float *wc_ws, *e_ws, *esum_ws;
};

#define CTXU_FLOATS 16896     // 64 rows x 264 u32 (skewed bf16 pairs)
#define SCR_FLOATS  3400      // P1: 1024+2112+256=3392 ; P3: 2128 ; P4: 2113
#define SMEM_FLOATS (CTXU_FLOATS + SCR_FLOATS + 64)

template<bool F32>
__device__ void run_all(const KP& p, float* smem) {
    const int bid = blockIdx.x;
    const int tid = threadIdx.x;
    const int b  = bid >> 3;
    const int j8 = bid & 7;           // cc for P1/P4, sg for P3
    const size_t XN = (size_t)Bb * Tt * Hh;
    const size_t HN = (size_t)Bb * Hh;
    u32*   ctxU = (u32*)smem;
    float* S    = smem + CTXU_FLOATS;
    float* cL   = smem + CTXU_FLOATS + SCR_FLOATS;   // 64 floats, persistent
    int ep = 0;

    // ---- one-time: stage ctx slice (b, sg=j8) into LDS (bf16-packed, skewed)
    for (int idx = tid; idx < 8192; idx += 512) {
        const int r = idx >> 7, q4 = (idx & 127) << 2;
        float4 v = ld4<F32>(p.ctx, ((size_t)((j8 << 6) + r) * Bb + b) * Hh + q4);
        const int w = q4 >> 1;
        const int sk = w >> 5;
        ctxU[r * 264 + w + sk]     = pack2bf(v.x, v.y);
        ctxU[r * 264 + w + 1 + sk] = pack2bf(v.z, v.w);
    }
    __syncthreads();

    for (int l = 0; l < 2; ++l) {
        const size_t wOffG  = (size_t)l * Hh * G4H;
        const size_t bOffG  = (size_t)l * G4H;
        const size_t wOffAi = (size_t)l * Hh * Hh;
        const size_t wOffAo = (size_t)l * 2 * Hh * Hh;
        const size_t offH1  = XN + (size_t)l * HN;
        const size_t offC1  = XN + 2 * HN + (size_t)l * HN;
        const size_t offAtt = XN + 4 * HN;
        const int writeAtt = l;

        for (int t = 0; t < Tt; ++t) {
            const int last = (t == Tt - 1);
            const size_t xrow = ((size_t)b * Tt + t) * Hh;

            { // ---- P1: gates -> hy, cy.  block = (b, cc): 64 cols over K=1024 ----
                const int cc = j8;
                float* xh  = S;                 // 1024
                float* red = S + 1024;          // [8][264]
                float* ga  = S + 3136;          // 256
                // stage x
                if (l == 0) {
                    if (tid < 128) {
                        float4 v = ld4<F32>(p.input, xrow + (tid << 2));
                        float* d = xh + (tid << 2);
                        d[0] = v.x; d[1] = v.y; d[2] = v.z; d[3] = v.w;
                    }
                } else {
                    if (tid < 256) {
                        if constexpr (F32) {
                            float2 v = ldb2((const float*)p.out + xrow + (tid << 1));
                            xh[(tid << 1)] = v.x; xh[(tid << 1) + 1] = v.y;
                        } else {
                            u32 u = ldbu((const u32*)p.out + (xrow >> 1) + tid);
                            xh[(tid << 1)] = bflo(u); xh[(tid << 1) + 1] = bfhi(u);
                        }
                    }
                }
                // stage h
                if (t == 0) {
                    if (tid < 128) {
                        float4 v = ld4<F32>(p.h0, (size_t)b * Hh + (tid << 2));
                        float* d = xh + 512 + (tid << 2);
                        d[0] = v.x; d[1] = v.y; d[2] = v.z; d[3] = v.w;
                    }
                } else {
                    if (tid < 256) {
                        u32 u = ldbu(p.hB + b * 256 + tid);
                        xh[512 + (tid << 1)] = bflo(u); xh[512 + (tid << 1) + 1] = bfhi(u);
                    }
                }
                // zero wc / esum for this timestep
                if (cc == 0) {
                    stb(p.wc_ws + (size_t)b * Hh + tid, 0.f);
                    if (tid == 0) stb(p.esum_ws + b, 0.f);
                }
                __syncthreads();

                const int kq  = tid >> 6;       // 0..7 (K chunk of 128; <4 -> Wi)
                const int rem = tid & 63;
                const int g   = rem >> 4;       // gate 0..3
                const int j4  = rem & 15;       // 4 cols
                const u16* Wb = (kq < 4) ? p.wiB : p.whB;
                size_t wi = wOffG + ((size_t)((kq & 3) << 7)) * G4H
                          + (size_t)((g << 9) + (cc << 6) + (j4 << 2));
                const float* xr = xh + (kq << 7);    // kq*128: x then h, contiguous
                float a0 = 0.f, a1 = 0.f, a2 = 0.f, a3 = 0.f;
                #pragma unroll 8
                for (int k = 0; k < 128; ++k) {
                    float4 w = ld4<false>(Wb, wi);
                    float xv = xr[k];
                    a0 += xv * w.x; a1 += xv * w.y; a2 += xv * w.z; a3 += xv * w.w;
                    wi += G4H;
                }
                float4 rv; rv.x = a0; rv.y = a1; rv.z = a2; rv.w = a3;
                *(float4*)(red + kq * 264 + (g << 6) + (j4 << 2)) = rv;
                __syncthreads();
                if (tid < 256) {
                    float s = 0.f;
                    #pragma unroll
                    for (int q = 0; q < 8; ++q) s += red[q * 264 + tid];
                    ga[tid] = s;
                }
                __syncthreads();
                if (tid < 64) {
                    const int j = tid;
                    const int n = (cc << 6) + j;
                    float gi = ga[j]        + ldin<F32>(p.bi, bOffG + n)        + ldin<F32>(p.bhp, bOffG + n);
                    float gf = ga[64 + j]   + ldin<F32>(p.bi, bOffG + 512 + n)  + ldin<F32>(p.bhp, bOffG + 512 + n);
                    float gg = ga[128 + j]  + ldin<F32>(p.bi, bOffG + 1024 + n) + ldin<F32>(p.bhp, bOffG + 1024 + n);
                    float go = ga[192 + j]  + ldin<F32>(p.bi, bOffG + 1536 + n) + ldin<F32>(p.bhp, bOffG + 1536 + n);
                    float ig = 1.f / (1.f + __expf(-gi));
                    float fg = 1.f / (1.f + __expf(-gf));
                    float g2 = tanhf(gg);
                    float og = 1.f / (1.f + __expf(-go));
                    float cp = (t == 0) ? ldin<F32>(p.c0, (size_t)b * Hh + n) : cL[j];
                    float cy = fg * cp + ig * g2;
                    float hy = og * tanhf(cy);
                    cL[j] = cy;
                    if (last) stout<F32>(p.out, offC1 + (size_t)b * Hh + n, cy);
                    float ohy = __shfl_xor(hy, 1);
                    if (!(j & 1))
                        stbu(p.hyB + b * 256 + (cc << 5) + (j >> 1), pack2bf(hy, ohy));
                }
            }
            gbar2(p.bars, ++ep);

            { // ---- P3: tgt-compute + scores + exp + wc partials.  block = (b, sg) ----
                const int sg = j8;
                float* hyL  = S;                // 512
                float* red2 = S + 512;          // [2][520]
                float* tgtL = S + 1552;         // 512
                float* eL   = S + 2064;         // 64
                if (tid < 256) {
                    u32 u = ldbu(p.hyB + b * 256 + tid);
                    hyL[(tid << 1)] = bflo(u); hyL[(tid << 1) + 1] = bfhi(u);
                }
                __syncthreads();
                { // tgt = hy @ Wa_in  (redundant per sg; Wa_in is L2-resident)
                    const int kh = tid >> 8, np = tid & 255;
                    const int n0 = np << 1;
                    size_t wi = wOffAi + ((size_t)(kh << 8)) * Hh + n0;
                    const float* hr = hyL + (kh << 8);
                    float a0 = 0.f, a1 = 0.f;
                    #pragma unroll 8
                    for (int k = 0; k < 256; ++k) {
                        u32 u = *(const u32*)(p.waiB + wi);
                        a0 += hr[k] * bflo(u); a1 += hr[k] * bfhi(u);
                        wi += Hh;
                    }
                    red2[kh * 520 + n0] = a0; red2[kh * 520 + n0 + 1] = a1;
                }
                __syncthreads();
                tgtL[tid] = red2[tid] + red2[520 + tid];
                __syncthreads();
                const int r = tid >> 3, kq = tid & 7;
                const u32* cw = ctxU + r * 264 + kq * 33;
                const float* tp = tgtL + (kq << 6);
                float d = 0.f;
                #pragma unroll 8
                for (int j = 0; j < 32; ++j) {
                    u32 u = cw[j];
                    d += __uint_as_float(u << 16)         * tp[2 * j]
                       + __uint_as_float(u & 0xffff0000u) * tp[2 * j + 1];
                }
                d += __shfl_xor(d, 1); d += __shfl_xor(d, 2); d += __shfl_xor(d, 4);
                if (kq == 0) {
                    float e = __expf(d);        // bounded: |score| <~ 60, safe in fp32
                    eL[r] = e;
                    stb(p.e_ws + (size_t)b * Ss + (sg << 6) + r, e);
                }
                __syncthreads();
                if (tid < 64) {
                    float w = eL[tid];
                    #pragma unroll
                    for (int o = 32; o > 0; o >>= 1) w += __shfl_xor(w, o);
                    if (tid == 0) atomicAdd(p.esum_ws + b, w);
                }
                const int wd = tid >> 1, hodd = tid & 1;
                const int woff = wd + (wd >> 5);
                float acc = 0.f;
                #pragma unroll 8
                for (int rr = 0; rr < 64; ++rr) {
                    u32 u = ctxU[rr * 264 + woff];
                    float v = hodd ? __uint_as_float(u & 0xffff0000u) : __uint_as_float(u << 16);
                    acc += eL[rr] * v;
                }
                atomicAdd(p.wc_ws + (size_t)b * Hh + tid, acc);
            }
            gbar2(p.bars, ++ep);

            { // ---- P4: h~ = tanh([wc,hy]@Wa_out).  block = (b, cc): 64 cols, K=1024 ----
                const int cc = j8;
                float* vL   = S;                // 1024
                float* red  = S + 1024;         // [16][68]
                float* invL = S + 2112;         // 1
                if (tid == 0) invL[0] = 1.f / ldb(p.esum_ws + b);
                if (tid < 256) {
                    float2 v = ldb2(p.wc_ws + (size_t)b * Hh + (tid << 1));
                    vL[(tid << 1)] = v.x; vL[(tid << 1) + 1] = v.y;
                    u32 u = ldbu(p.hyB + b * 256 + tid);
                    vL[512 + (tid << 1)] = bflo(u); vL[512 + (tid << 1) + 1] = bfhi(u);
                }
                __syncthreads();
                const float inv = invL[0];
                vL[tid] *= inv;                 // tid 0..511 = exactly the wc half
                __syncthreads();
                const int ko = tid >> 5;        // 0..15 (64-row K chunks)
                const int jp = tid & 31;        // col pair
                const int n0 = (cc << 6) + (jp << 1);
                size_t wi = wOffAo + ((size_t)(ko << 6)) * Hh + n0;
                const float* vr = vL + (ko << 6);
                float a0 = 0.f, a1 = 0.f;
                #pragma unroll 8
                for (int k = 0; k < 64; ++k) {
                    u32 u = *(const u32*)(p.waoB + wi);
                    a0 += vr[k] * bflo(u); a1 += vr[k] * bfhi(u);
                    wi += Hh;
                }
                red[ko * 68 + (jp << 1)] = a0; red[ko * 68 + (jp << 1) + 1] = a1;
                __syncthreads();
                if (tid < 64) {
                    float s = 0.f;
                    #pragma unroll
                    for (int q = 0; q < 16; ++q) s += red[q * 68 + tid];
                    float th = tanhf(s);
                    const int n2 = (cc << 6) + tid;
                    float oth = __shfl_xor(th, 1);
                    if (l == 0) {
                        // bypass pair store: layer-1 reads this cross-XCD, coherent by construction
                        if (!(tid & 1)) stout2b<F32>(p.out, xrow + n2, th, oth);
                    } else {
                        stout<F32>(p.out, xrow + n2, th);
                    }
                    if (last) stout<F32>(p.out, offH1 + (size_t)b * Hh + n2, th);
                    if (!(tid & 1))
                        stbu(p.hB + b * 256 + (cc << 5) + (tid >> 1), pack2bf(th, oth));
                    if (writeAtt) {
                        float pv = ldb(p.e_ws + (size_t)b * Ss + n2) * inv;
                        stout<F32>(p.out, offAtt + (size_t)n2 * (Tt * Bb) + (size_t)t * Bb + b, pv);
                    }
                }
            }
            gbar2(p.bars, ++ep);
        }
    }
}

__global__ __launch_bounds__(512, 2) void kmain(KP p) {
    __shared__ float smem[SMEM_FLOATS];
    if (*p.flag) run_all<true >(p, smem);
    else         run_all<false>(p, smem);
}

// ===========================================================================
// Fallback path: original per-timestep kernels (proven correct)
// ===========================================================================
template<bool F32>
__device__ __forceinline__ void gates_body(
    const void* xsrc, const void* h0, const void* c0,
    const void* Wi, const void* bi, const void* Wh, const void* bh,
    size_t wOff, size_t bOff,
    const float* h_ws, float* c_ws, float* hy_ws,
    void* out, unsigned long long offC1, int t, int writeC1)
{
    __shared__ float xh[1024];
    __shared__ float red[4][32][8];
    __shared__ float ga[4][32];

    const int b  = blockIdx.x >> 4;
    const int jc = blockIdx.x & 15;
    const int tid = threadIdx.x;

    const size_t xrow = ((size_t)b * Tt + t) * Hh;
    for (int i = tid; i < 512; i += 256) xh[i] = ldin<F32>(xsrc, xrow + i);
    if (t == 0) {
        for (int i = tid; i < 512; i += 256) xh[512 + i] = ldin<F32>(h0, (size_t)b * Hh + i);
    } else {
        for (int i = tid; i < 512; i += 256) xh[512 + i] = h_ws[b * Hh + i];
    }
    __syncthreads();

    const int jl = tid & 31;
    const int kq = tid >> 5;
    const int j  = jc * 32 + jl;
    const void* Wbase = (kq < 4) ? Wi : Wh;
    const int k0 = (kq & 3) * 128;
    const int xoff = (kq < 4) ? 0 : 512;

    float a0 = 0.f, a1 = 0.f, a2 = 0.f, a3 = 0.f;
    size_t widx = wOff + (size_t)k0 * G4H + j;
    #pragma unroll 4
    for (int k = 0; k < 128; ++k) {
        float xv = xh[xoff + k0 + k];
        a0 += xv * ldin<F32>(Wbase, widx + 0 * Hh);
        a1 += xv * ldin<F32>(Wbase, widx + 1 * Hh);
        a2 += xv * ldin<F32>(Wbase, widx + 2 * Hh);
        a3 += xv * ldin<F32>(Wbase, widx + 3 * Hh);
        widx += G4H;
    }
    red[0][jl][kq] = a0; red[1][jl][kq] = a1;
    red[2][jl][kq] = a2; red[3][jl][kq] = a3;
    __syncthreads();

    if (tid < 128) {
        int g = tid >> 5, jj = tid & 31;
        float s = 0.f;
        #pragma unroll
        for (int q = 0; q < 8; ++q) s += red[g][jj][q];
        ga[g][jj] = s;
    }
    __syncthreads();

    if (tid < 32) {
        int jj = tid;
        int n = jc * 32 + jj;
        float gi = ga[0][jj] + ldin<F32>(bi, bOff + 0 * Hh + n) + ldin<F32>(bh, bOff + 0 * Hh + n);
        float gf = ga[1][jj] + ldin<F32>(bi, bOff + 1 * Hh + n) + ldin<F32>(bh, bOff + 1 * Hh + n);
        float gg = ga[2][jj] + ldin<F32>(bi, bOff + 2 * Hh + n) + ldin<F32>(bh, bOff + 2 * Hh + n);
        float go = ga[3][jj] + ldin<F32>(bi, bOff + 3 * Hh + n) + ldin<F32>(bh, bOff + 3 * Hh + n);
        float ig = 1.f / (1.f + __expf(-gi));
        float fg = 1.f / (1.f + __expf(-gf));
        float g2 = tanhf(gg);
        float og = 1.f / (1.f + __expf(-go));
        float cp = (t == 0) ? ldin<F32>(c0, (size_t)b * Hh + n) : c_ws[b * Hh + n];
        float cy = fg * cp + ig * g2;
        float hy = og * tanhf(cy);
        c_ws[b * Hh + n]  = cy;
        hy_ws[b * Hh + n] = hy;
        if (writeC1) stout<F32>(out, offC1 + (size_t)b * Hh + n, cy);
    }
}

__global__ __launch_bounds__(256) void k_gates(
    const int* flag, const void* xsrc, const void* h0, const void* c0,
    const void* Wi, const void* bi, const void* Wh, const void* bh,
    unsigned long long wOff, unsigned long long bOff,
    const float* h_ws, float* c_ws, float* hy_ws,
    void* out, unsigned long long offC1, int t, int writeC1)
{
    if (*flag) gates_body<true >(xsrc, h0, c0, Wi, bi, Wh, bh, wOff, bOff, h_ws, c_ws, hy_ws, out, offC1, t, writeC1);
    else       gates_body<false>(xsrc, h0, c0, Wi, bi, Wh, bh, wOff, bOff, h_ws, c_ws, hy_ws, out, offC1, t, writeC1);
}

template<bool F32>
__device__ __forceinline__ void target_body(
    const float* hy_ws, const void* Wa_in, size_t wOff, float* tgt_ws)
{
    __shared__ float hyL[512];
    __shared__ float red[64][4];

    const int b  = blockIdx.x >> 3;
    const int nc = blockIdx.x & 7;
    const int tid = threadIdx.x;

    for (int i = tid; i < 512; i += 256) hyL[i] = hy_ws[b * Hh + i];
    __syncthreads();

    const int nl = tid & 63;
    const int kq = tid >> 6;
    const int n  = nc * 64 + nl;
    const int kb = kq * 128;
    float acc = 0.f;
    #pragma unroll 4
    for (int k = 0; k < 128; ++k)
        acc += hyL[kb + k] * ldin<F32>(Wa_in, wOff + (size_t)(kb + k) * Hh + n);
    red[nl][kq] = acc;
    __syncthreads();

    if (tid < 64) {
        float s = red[tid][0] + red[tid][1] + red[tid][2] + red[tid][3];
        tgt_ws[b * Hh + nc * 64 + tid] = s;
    }
}

__global__ __launch_bounds__(256) void k_target(
    const int* flag, const float* hy_ws, const void* Wa_in,
    unsigned long long wOff, float* tgt_ws)
{
    if (*flag) target_body<true >(hy_ws, Wa_in, wOff, tgt_ws);
    else       target_body<false>(hy_ws, Wa_in, wOff, tgt_ws);
}

template<bool F32>
__device__ __forceinline__ void scores_body(
    const void* ctx, const float* tgt_ws, float* sc_ws)
{
    const int w    = threadIdx.x >> 6;
    const int lane = threadIdx.x & 63;
    const int id = blockIdx.x * 4 + w;
    const int b = id & 31;
    const int s = id >> 5;

    const size_t base = ((size_t)s * Bb + b) * Hh + lane * 8;
    const float* tp = tgt_ws + (size_t)b * Hh + lane * 8;
    float d = 0.f;
    #pragma unroll
    for (int i = 0; i < 8; ++i) d += ldin<F32>(ctx, base + i) * tp[i];
    #pragma unroll
    for (int o = 32; o > 0; o >>= 1) d += __shfl_xor(d, o);
    if (lane == 0) sc_ws[b * Ss + s] = d;
}

__global__ __launch_bounds__(256) void k_scores(
    const int* flag, const void* ctx, const float* tgt_ws, float* sc_ws)
{
    if (*flag) scores_body<true >(ctx, tgt_ws, sc_ws);
    else       scores_body<false>(ctx, tgt_ws, sc_ws);
}

template<bool F32>
__device__ __forceinline__ void wc_body(
    const void* ctx, const float* sc_ws, float* wc_ws,
    void* out, unsigned long long offAtt, int t, int writeAtt)
{
    __shared__ float scL[512];
    __shared__ float red[256];

    const int b   = blockIdx.x >> 2;
    const int hc  = blockIdx.x & 3;
    const int tid = threadIdx.x;

    scL[tid]       = sc_ws[b * Ss + tid];
    scL[tid + 256] = sc_ws[b * Ss + tid + 256];
    __syncthreads();

    red[tid] = fmaxf(scL[tid], scL[tid + 256]);
    __syncthreads();
    for (int o = 128; o > 0; o >>= 1) {
        if (tid < o) red[tid] = fmaxf(red[tid], red[tid + o]);
        __syncthreads();
    }
    const float M = red[0];
    __syncthreads();

    red[tid] = __expf(scL[tid] - M) + __expf(scL[tid + 256] - M);
    __syncthreads();
    for (int o = 128; o > 0; o >>= 1) {
        if (tid < o) red[tid] += red[tid + o];
        __syncthreads();
    }
    const float inv = 1.f / red[0];
    __syncthreads();

    const int h    = hc * 128 + (tid & 127);
    const int half = tid >> 7;
    float acc = 0.f;
    const int s0 = half * 256;
    for (int s = s0; s < s0 + 256; ++s)
        acc += __expf(scL[s] - M) * ldin<F32>(ctx, ((size_t)s * Bb + b) * Hh + h);

    red[tid] = acc;
    __syncthreads();
    if (half == 0)
        wc_ws[b * Hh + h] = (red[tid] + red[tid + 128]) * inv;

    if (writeAtt && hc == 0) {
        float p0 = __expf(scL[tid] - M) * inv;
        float p1 = __expf(scL[tid + 256] - M) * inv;
        stout<F32>(out, offAtt + (size_t)tid         * (Tt * Bb) + (size_t)t * Bb + b, p0);
        stout<F32>(out, offAtt + (size_t)(tid + 256) * (Tt * Bb) + (size_t)t * Bb + b, p1);
    }
}

__global__ __launch_bounds__(256) void k_wc(
    const int* flag, const void* ctx, const float* sc_ws, float* wc_ws,
    void* out, unsigned long long offAtt, int t, int writeAtt)
{
    if (*flag) wc_body<true >(ctx, sc_ws, wc_ws, out, offAtt, t, writeAtt);
    else       wc_body<false>(ctx, sc_ws, wc_ws, out, offAtt, t, writeAtt);
}

template<bool F32>
__device__ __forceinline__ void out_body(
    const float* hy_ws, const float* wc_ws, const void* Wa_out, size_t wOff,
    float* h_ws, void* out, unsigned long long offH1, int t, int writeH1)
{
    __shared__ float vL[1024];
    __shared__ float red[32][8];

    const int b  = blockIdx.x >> 4;
    const int nc = blockIdx.x & 15;
    const int tid = threadIdx.x;

    for (int h = tid; h < 512; h += 256) {
        vL[h]       = wc_ws[b * Hh + h];
        vL[512 + h] = hy_ws[b * Hh + h];
    }
    __syncthreads();

    const int nl = tid & 31;
    const int kq = tid >> 5;
    const int n  = nc * 32 + nl;
    const int kb = kq * 128;
    float acc = 0.f;
    #pragma unroll 4
    for (int k = 0; k < 128; ++k)
        acc += vL[kb + k] * ldin<F32>(Wa_out, wOff + (size_t)(kb + k) * Hh + n);
    red[nl][kq] = acc;
    __syncthreads();

    if (tid < 32) {
        float s = 0.f;
        #pragma unroll
        for (int q = 0; q < 8; ++q) s += red[tid][q];
        float th = tanhf(s);
        int n2 = nc * 32 + tid;
        h_ws[b * Hh + n2] = th;
        stout<F32>(out, ((size_t)b * Tt + t) * Hh + n2, th);
        if (writeH1) stout<F32>(out, offH1 + (size_t)b * Hh + n2, th);
    }
}

__global__ __launch_bounds__(256) void k_out(
    const int* flag, const float* hy_ws, const float* wc_ws, const void* Wa_out,
    unsigned long long wOff, float* h_ws, void* out,
    unsigned long long offH1, int t, int writeH1)
{
    if (*flag) out_body<true >(hy_ws, wc_ws, Wa_out, wOff, h_ws, out, offH1, t, writeH1);
    else       out_body<false>(hy_ws, wc_ws, Wa_out, wOff, h_ws, out, offH1, t, writeH1);
}

// ---------------------------------------------------------------------------
extern "C" void kernel_launch(void* const* d_in, const int* in_sizes, int n_in,
                              void* d_out, int out_size, void* d_ws, size_t ws_size,
                              hipStream_t stream)
{
    const void* input  = d_in[0];
    const void* h0     = d_in[1];
    const void* c0     = d_in[2];
    const void* ctx    = d_in[3];
    const void* Wi     = d_in[4];
    const void* bi     = d_in[5];
    const void* Wh     = d_in[6];
    const void* bh     = d_in[7];
    const void* Wa_in  = d_in[8];
    const void* Wa_out = d_in[9];

    const size_t XN = (size_t)Bb * Tt * Hh;
    const size_t HN = (size_t)Bb * Hh;
    const unsigned long long offH1base = XN;
    const unsigned long long offC1base = XN + 2 * HN;
    const unsigned long long offAtt    = XN + 4 * HN;

    char* base = (char*)d_ws;
    int* flag  = (int*)base;
    int* bars  = (int*)(base + 128);                   // 34 slots x 128 B
    float* f   = (float*)(base + 128 + 34 * 128);
    float* h_ws    = f; f += HN;                       // fallback only
    float* c_ws    = f; f += HN;                       // fallback only
    float* hy_ws   = f; f += HN;                       // fallback only
    float* tgt_ws  = f; f += HN;                       // fallback only
    float* wc_ws   = f; f += HN;
    float* e_ws    = f; f += (size_t)Bb * Ss;
    float* sc_ws   = f; f += (size_t)Bb * Ss;          // fallback only
    float* esum_ws = f; f += 64;

    size_t off = ((size_t)((char*)f - base) + 255) & ~(size_t)255;
    u32* hB   = (u32*)(base + off); off += 32 * 256 * 4;
    u32* hyB  = (u32*)(base + off); off += 32 * 256 * 4;
    off = (off + 255) & ~(size_t)255;
    const size_t NWI  = (size_t)2 * 512 * 2048;
    const size_t NWH  = (size_t)2 * 512 * 2048;
    const size_t NWAI = (size_t)2 * 512 * 512;
    const size_t NWAO = (size_t)2 * 1024 * 512;
    u16* wiB  = (u16*)(base + off); off += NWI * 2;
    u16* whB  = (u16*)(base + off); off += NWH * 2;
    u16* waiB = (u16*)(base + off); off += NWAI * 2;
    u16* waoB = (u16*)(base + off); off += NWAO * 2;
    const int fits = (ws_size >= off) ? 1 : 0;

    k_detect<<<dim3(1), dim3(256), 0, stream>>>(ctx, flag, bars);

    hipError_t err = hipErrorUnknown;
    if (fits) {
        k_cvt<<<dim3((unsigned)(NWI  / 2048)), dim3(256), 0, stream>>>(flag, Wi,     wiB);
        k_cvt<<<dim3((unsigned)(NWH  / 2048)), dim3(256), 0, stream>>>(flag, Wh,     whB);
        k_cvt<<<dim3((unsigned)(NWAI / 2048)), dim3(256), 0, stream>>>(flag, Wa_in,  waiB);
        k_cvt<<<dim3((unsigned)(NWAO / 2048)), dim3(256), 0, stream>>>(flag, Wa_out, waoB);

        KP hp;
        hp.input = input; hp.h0 = h0; hp.c0 = c0; hp.ctx = ctx;
        hp.bi = bi; hp.bhp = bh;
        hp.wiB = wiB; hp.whB = whB; hp.waiB = waiB; hp.waoB = waoB;
        hp.out = d_out; hp.flag = flag; hp.bars = bars;
        hp.hB = hB; hp.hyB = hyB;
        hp.wc_ws = wc_ws; hp.e_ws = e_ws; hp.esum_ws = esum_ws;

        void* kargs[] = { &hp };
        err = hipLaunchCooperativeKernel(kmain, dim3(NBLK), dim3(512), kargs, 0u, stream);
    }

    if (err != hipSuccess) {
        (void)hipGetLastError();   // clear error state
        // Fallback: proven per-timestep multi-kernel path
        for (int l = 0; l < 2; ++l) {
            const void* xsrc = (l == 0) ? input : (const void*)d_out;
            const unsigned long long wOffG  = (unsigned long long)l * Hh * G4H;
            const unsigned long long bOffG  = (unsigned long long)l * G4H;
            const unsigned long long wOffAi = (unsigned long long)l * Hh * Hh;
            const unsigned long long wOffAo = (unsigned long long)l * 2 * Hh * Hh;
            const unsigned long long offH1  = offH1base + (unsigned long long)l * HN;
            const unsigned long long offC1  = offC1base + (unsigned long long)l * HN;

            for (int t = 0; t < Tt; ++t) {
                const int last = (t == Tt - 1) ? 1 : 0;
                k_gates<<<dim3(512), dim3(256), 0, stream>>>(
                    flag, xsrc, h0, c0, Wi, bi, Wh, bh, wOffG, bOffG,
                    h_ws, c_ws, hy_ws, d_out, offC1, t, last);
                k_target<<<dim3(256), dim3(256), 0, stream>>>(
                    flag, hy_ws, Wa_in, wOffAi, tgt_ws);
                k_scores<<<dim3(4096), dim3(256), 0, stream>>>(
                    flag, ctx, tgt_ws, sc_ws);
                k_wc<<<dim3(128), dim3(256), 0, stream>>>(
                    flag, ctx, sc_ws, wc_ws, d_out, offAtt, t, l);
                k_out<<<dim3(512), dim3(256), 0, stream>>>(
                    flag, hy_ws, wc_ws, Wa_out, wOffAo, h_ws, d_out, offH1, t, last);
            }
        }
    }
}

// Round 8
// 14126.892 us; speedup vs baseline: 2.0108x; 1.2197x over previous
//
#include <hip/hip_runtime.h>

typedef unsigned short u16;
typedef unsigned int   u32;
typedef unsigned long long u64;

#define Bb   32
#define Tt   256
#define Ss   512
#define Hh   512
#define G4H  2048
#define NBLK 256

// ---- dtype-polymorphic load/store: F32 ? fp32 : bf16 ------------------------
template<bool F32>
__device__ __forceinline__ float ldin(const void* p, size_t i) {
    if constexpr (F32) {
        return ((const float*)p)[i];
    } else {
        u32 v = ((u32)((const u16*)p)[i]) << 16;
        return __uint_as_float(v);
    }
}
template<bool F32>
__device__ __forceinline__ void stout(void* p, size_t i, float f) {
    if constexpr (F32) {
        ((float*)p)[i] = f;
    } else {
        u32 x = __float_as_uint(f);
        u32 r = x + 0x7fffu + ((x >> 16) & 1u);   // RNE
        ((u16*)p)[i] = (u16)(r >> 16);
    }
}
template<bool F32>
__device__ __forceinline__ float4 ld4(const void* p, size_t i) {
    if constexpr (F32) {
        return *(const float4*)((const float*)p + i);
    } else {
        ushort4 u = *(const ushort4*)((const u16*)p + i);
        float4 f;
        f.x = __uint_as_float((u32)u.x << 16);
        f.y = __uint_as_float((u32)u.y << 16);
        f.z = __uint_as_float((u32)u.z << 16);
        f.w = __uint_as_float((u32)u.w << 16);
        return f;
    }
}
__device__ __forceinline__ u32 pack2bf(float a, float b) {
    u32 xa = __float_as_uint(a), xb = __float_as_uint(b);
    u32 ra = (xa + 0x7fffu + ((xa >> 16) & 1u)) >> 16;
    u32 rb = (xb + 0x7fffu + ((xb >> 16) & 1u)) & 0xffff0000u;
    return ra | rb;
}
__device__ __forceinline__ float bflo(u32 u) { return __uint_as_float(u << 16); }
__device__ __forceinline__ float bfhi(u32 u) { return __uint_as_float(u & 0xffff0000u); }

// ---- cache-bypassing (coherence-point) accessors for mutable shared state ---
__device__ __forceinline__ float ldb(const float* p) {
    return __hip_atomic_load(p, __ATOMIC_RELAXED, __HIP_MEMORY_SCOPE_AGENT);
}
__device__ __forceinline__ void stb(float* p, float v) {
    __hip_atomic_store(p, v, __ATOMIC_RELAXED, __HIP_MEMORY_SCOPE_AGENT);
}
__device__ __forceinline__ float2 ldb2(const float* p) {
    u64 v = __hip_atomic_load((const u64*)p, __ATOMIC_RELAXED, __HIP_MEMORY_SCOPE_AGENT);
    float2 r;
    r.x = __uint_as_float((u32)v);
    r.y = __uint_as_float((u32)(v >> 32));
    return r;
}
__device__ __forceinline__ u32 ldbu(const u32* p) {
    return __hip_atomic_load(p, __ATOMIC_RELAXED, __HIP_MEMORY_SCOPE_AGENT);
}
__device__ __forceinline__ void stbu(u32* p, u32 v) {
    __hip_atomic_store(p, v, __ATOMIC_RELAXED, __HIP_MEMORY_SCOPE_AGENT);
}
// bypass pair-store into the output buffer (layer-0 x handoff; no fences needed)
template<bool F32>
__device__ __forceinline__ void stout2b(void* p, size_t i, float a, float b) {
    if constexpr (F32) {
        u64 v = (u64)__float_as_uint(a) | ((u64)__float_as_uint(b) << 32);
        __hip_atomic_store((u64*)((float*)p + i), v, __ATOMIC_RELAXED, __HIP_MEMORY_SCOPE_AGENT);
    } else {
        stbu((u32*)p + (i >> 1), pack2bf(a, b));
    }
}

// ---- per-b-group barrier: 8 blocks (one per XCD), monotonic counter ---------
// __syncthreads drains each wave's vmcnt before s_barrier, so all bypass stores
// are at the coherence point before tid0 arrives.
__device__ __forceinline__ void bbar(int* ctr, int target) {
    __syncthreads();
    if (threadIdx.x == 0) {
        asm volatile("s_waitcnt vmcnt(0)" ::: "memory");
        __hip_atomic_fetch_add(ctr, 1, __ATOMIC_RELAXED, __HIP_MEMORY_SCOPE_AGENT);
        while (__hip_atomic_load(ctr, __ATOMIC_RELAXED, __HIP_MEMORY_SCOPE_AGENT) < target)
            __builtin_amdgcn_s_sleep(1);
    }
    __syncthreads();
}

// ---------------------------------------------------------------------------
// K0: dtype detector + barrier-state init
// ---------------------------------------------------------------------------
__global__ __launch_bounds__(256) void k_detect(const void* ctx, int* flag, int* bbars) {
    __shared__ int c_sh;
    if (threadIdx.x == 0) c_sh = 0;
    __syncthreads();
    const u16* p = (const u16*)ctx;
    int c = 0;
    for (int i = threadIdx.x; i < 16384; i += 256) {
        int e = (p[i] >> 7) & 0xFF;
        if (e >= 0xC8) c++;
    }
    atomicAdd(&c_sh, c);
    __syncthreads();
    if (threadIdx.x == 0) *flag = (c_sh > 64) ? 1 : 0;
    if (threadIdx.x < 32) bbars[threadIdx.x * 64] = 0;
}

// ---------------------------------------------------------------------------
// K0b: generic -> bf16 conversion (copy-through if already bf16).
// ---------------------------------------------------------------------------
__global__ __launch_bounds__(256) void k_cvt(const int* flag, const void* src, u16* dst) {
    const size_t i = ((size_t)blockIdx.x * 256 + threadIdx.x) * 8;
    if (*flag) {
        const float* s = (const float*)src + i;
        float4 v0 = *(const float4*)(s);
        float4 v1 = *(const float4*)(s + 4);
        uint4 o;
        o.x = pack2bf(v0.x, v0.y);
        o.y = pack2bf(v0.z, v0.w);
        o.z = pack2bf(v1.x, v1.y);
        o.w = pack2bf(v1.z, v1.w);
        *(uint4*)(dst + i) = o;
    } else {
        *(uint4*)(dst + i) = *(const uint4*)((const u16*)src + i);
    }
}

// ===========================================================================
// Fused persistent kernel: 256 blocks x 512 threads
//  - fixed block identity (b = bid>>3, j = bid&7); XCD = j for all phases
//  - weights bf16, per-XCD slices CONTIGUOUS -> truly L2-resident (R7-proven)
//  - 3 phases/ts; per-b 8-block barriers (all deps are per-b)
//  - layer-0 x handoff via bypass stores into out (no fences)
// ===========================================================================
struct KP {
    const void *input, *h0, *c0, *ctx, *bi, *bhp;
    const u16 *wiB, *whB, *waiB, *waoB;
    void* out;
    const int* flag;
    int* bbars;
    u32 *hB, *hyB;
    float *wc_ws, *e_ws, *esum_ws;
};

#define CTXU_FLOATS 16896     // 64 rows x 264 u32 (skewed bf16 pairs)
#define SCR_FLOATS  3400      // P1: 3392 ; P3: 2144 ; P4: 2113
#define SMEM_FLOATS (CTXU_FLOATS + SCR_FLOATS + 64)

template<bool F32>
__device__ void run_all(const KP& p, float* smem) {
    const int bid = blockIdx.x;
    const int tid = threadIdx.x;
    const int b  = bid >> 3;
    const int j8 = bid & 7;           // cc for P1/P4, sg for P3
    const size_t XN = (size_t)Bb * Tt * Hh;
    const size_t HN = (size_t)Bb * Hh;
    u32*   ctxU = (u32*)smem;
    float* S    = smem + CTXU_FLOATS;
    float* cL   = smem + CTXU_FLOATS + SCR_FLOATS;   // 64 floats, persistent
    int*   ctr  = p.bbars + b * 64;
    int ep = 0;

    // ---- one-time: stage ctx slice (b, sg=j8) into LDS (bf16-packed, skewed)
    for (int idx = tid; idx < 8192; idx += 512) {
        const int r = idx >> 7, q4 = (idx & 127) << 2;
        float4 v = ld4<F32>(p.ctx, ((size_t)((j8 << 6) + r) * Bb + b) * Hh + q4);
        const int w = q4 >> 1;
        const int sk = w >> 5;
        ctxU[r * 264 + w + sk]     = pack2bf(v.x, v.y);
        ctxU[r * 264 + w + 1 + sk] = pack2bf(v.z, v.w);
    }
    __syncthreads();

    for (int l = 0; l < 2; ++l) {
        const size_t wOffG  = (size_t)l * Hh * G4H;
        const size_t bOffG  = (size_t)l * G4H;
        const size_t wOffAi = (size_t)l * Hh * Hh;
        const size_t wOffAo = (size_t)l * 2 * Hh * Hh;
        const size_t offH1  = XN + (size_t)l * HN;
        const size_t offC1  = XN + 2 * HN + (size_t)l * HN;
        const size_t offAtt = XN + 4 * HN;
        const int writeAtt = l;

        for (int t = 0; t < Tt; ++t) {
            const int last = (t == Tt - 1);
            const size_t xrow = ((size_t)b * Tt + t) * Hh;

            { // ---- P1: gates -> hy, cy.  block = (b, cc): 64 cols over K=1024 ----
                const int cc = j8;
                float* xh  = S;                 // 1024
                float* red = S + 1024;          // [8][264]
                float* ga  = S + 3136;          // 256
                // stage x
                if (l == 0) {
                    if (tid < 128) {
                        float4 v = ld4<F32>(p.input, xrow + (tid << 2));
                        float* d = xh + (tid << 2);
                        d[0] = v.x; d[1] = v.y; d[2] = v.z; d[3] = v.w;
                    }
                } else {
                    if (tid < 256) {
                        if constexpr (F32) {
                            float2 v = ldb2((const float*)p.out + xrow + (tid << 1));
                            xh[(tid << 1)] = v.x; xh[(tid << 1) + 1] = v.y;
                        } else {
                            u32 u = ldbu((const u32*)p.out + (xrow >> 1) + tid);
                            xh[(tid << 1)] = bflo(u); xh[(tid << 1) + 1] = bfhi(u);
                        }
                    }
                }
                // stage h
                if (t == 0) {
                    if (tid < 128) {
                        float4 v = ld4<F32>(p.h0, (size_t)b * Hh + (tid << 2));
                        float* d = xh + 512 + (tid << 2);
                        d[0] = v.x; d[1] = v.y; d[2] = v.z; d[3] = v.w;
                    }
                } else {
                    if (tid < 256) {
                        u32 u = ldbu(p.hB + b * 256 + tid);
                        xh[512 + (tid << 1)] = bflo(u); xh[512 + (tid << 1) + 1] = bfhi(u);
                    }
                }
                // zero wc / esum for this timestep
                if (cc == 0) {
                    stb(p.wc_ws + (size_t)b * Hh + tid, 0.f);
                    if (tid == 0) stb(p.esum_ws + b, 0.f);
                }
                __syncthreads();

                const int kq  = tid >> 6;       // 0..7 (K chunk of 128; <4 -> Wi)
                const int rem = tid & 63;
                const int g   = rem >> 4;       // gate 0..3
                const int j4  = rem & 15;       // 4 cols
                const u16* Wb = (kq < 4) ? p.wiB : p.whB;
                size_t wi = wOffG + ((size_t)((kq & 3) << 7)) * G4H
                          + (size_t)((g << 9) + (cc << 6) + (j4 << 2));
                const float* xr = xh + (kq << 7);    // kq*128: x then h, contiguous
                float a0 = 0.f, a1 = 0.f, a2 = 0.f, a3 = 0.f;
                #pragma unroll 8
                for (int k = 0; k < 128; ++k) {
                    float4 w = ld4<false>(Wb, wi);
                    float xv = xr[k];
                    a0 += xv * w.x; a1 += xv * w.y; a2 += xv * w.z; a3 += xv * w.w;
                    wi += G4H;
                }
                float4 rv; rv.x = a0; rv.y = a1; rv.z = a2; rv.w = a3;
                *(float4*)(red + kq * 264 + (g << 6) + (j4 << 2)) = rv;
                __syncthreads();
                if (tid < 256) {
                    float s = 0.f;
                    #pragma unroll
                    for (int q = 0; q < 8; ++q) s += red[q * 264 + tid];
                    ga[tid] = s;
                }
                __syncthreads();
                if (tid < 64) {
                    const int j = tid;
                    const int n = (cc << 6) + j;
                    float gi = ga[j]        + ldin<F32>(p.bi, bOffG + n)        + ldin<F32>(p.bhp, bOffG + n);
                    float gf = ga[64 + j]   + ldin<F32>(p.bi, bOffG + 512 + n)  + ldin<F32>(p.bhp, bOffG + 512 + n);
                    float gg = ga[128 + j]  + ldin<F32>(p.bi, bOffG + 1024 + n) + ldin<F32>(p.bhp, bOffG + 1024 + n);
                    float go = ga[192 + j]  + ldin<F32>(p.bi, bOffG + 1536 + n) + ldin<F32>(p.bhp, bOffG + 1536 + n);
                    float ig = 1.f / (1.f + __expf(-gi));
                    float fg = 1.f / (1.f + __expf(-gf));
                    float g2 = tanhf(gg);
                    float og = 1.f / (1.f + __expf(-go));
                    float cp = (t == 0) ? ldin<F32>(p.c0, (size_t)b * Hh + n) : cL[j];
                    float cy = fg * cp + ig * g2;
                    float hy = og * tanhf(cy);
                    cL[j] = cy;
                    if (last) stout<F32>(p.out, offC1 + (size_t)b * Hh + n, cy);
                    float ohy = __shfl_xor(hy, 1);
                    if (!(j & 1))
                        stbu(p.hyB + b * 256 + (cc << 5) + (j >> 1), pack2bf(hy, ohy));
                }
            }
            bbar(ctr, (++ep) << 3);

            { // ---- P3: tgt-compute + scores + exp + wc partials.  block = (b, sg) ----
                const int sg = j8;
                float* hyL  = S;                // 512
                float* red2 = S + 512;          // [2][520]
                float* tgtL = S + 1552;         // [8][66] skewed (bank-conflict fix)
                float* eL   = S + 2080;         // 64
                if (tid < 256) {
                    u32 u = ldbu(p.hyB + b * 256 + tid);
                    hyL[(tid << 1)] = bflo(u); hyL[(tid << 1) + 1] = bfhi(u);
                }
                __syncthreads();
                { // tgt = hy @ Wa_in  (redundant per sg; Wa_in is L2-resident)
                    const int kh = tid >> 8, np = tid & 255;
                    const int n0 = np << 1;
                    size_t wi = wOffAi + ((size_t)(kh << 8)) * Hh + n0;
                    const float* hr = hyL + (kh << 8);
                    float a0 = 0.f, a1 = 0.f;
                    #pragma unroll 8
                    for (int k = 0; k < 256; ++k) {
                        u32 u = *(const u32*)(p.waiB + wi);
                        a0 += hr[k] * bflo(u); a1 += hr[k] * bfhi(u);
                        wi += Hh;
                    }
                    red2[kh * 520 + n0] = a0; red2[kh * 520 + n0 + 1] = a1;
                }
                __syncthreads();
                tgtL[(tid >> 6) * 66 + (tid & 63)] = red2[tid] + red2[520 + tid];
                __syncthreads();
                const int r = tid >> 3, kq = tid & 7;
                const u32* cw = ctxU + r * 264 + kq * 33;
                const float* tp = tgtL + kq * 66;
                float d = 0.f;
                #pragma unroll 8
                for (int j = 0; j < 32; ++j) {
                    u32 u = cw[j];
                    d += __uint_as_float(u << 16)         * tp[2 * j]
                       + __uint_as_float(u & 0xffff0000u) * tp[2 * j + 1];
                }
                d += __shfl_xor(d, 1); d += __shfl_xor(d, 2); d += __shfl_xor(d, 4);
                if (kq == 0) {
                    float e = __expf(d);        // bounded: |score| <~ 60, safe in fp32
                    eL[r] = e;
                    stb(p.e_ws + (size_t)b * Ss + (sg << 6) + r, e);
                }
                __syncthreads();
                if (tid < 64) {
                    float w = eL[tid];
                    #pragma unroll
                    for (int o = 32; o > 0; o >>= 1) w += __shfl_xor(w, o);
                    if (tid == 0) atomicAdd(p.esum_ws + b, w);
                }
                const int wd = tid >> 1, hodd = tid & 1;
                const int woff = wd + (wd >> 5);
                float acc = 0.f;
                #pragma unroll 8
                for (int rr = 0; rr < 64; ++rr) {
                    u32 u = ctxU[rr * 264 + woff];
                    float v = hodd ? __uint_as_float(u & 0xffff0000u) : __uint_as_float(u << 16);
                    acc += eL[rr] * v;
                }
                atomicAdd(p.wc_ws + (size_t)b * Hh + tid, acc);
            }
            bbar(ctr, (++ep) << 3);

            { // ---- P4: h~ = tanh([wc,hy]@Wa_out).  block = (b, cc): 64 cols, K=1024 ----
                const int cc = j8;
                float* vL   = S;                // 1024
                float* red  = S + 1024;         // [16][68]
                float* invL = S + 2112;         // 1
                if (tid == 0) invL[0] = 1.f / ldb(p.esum_ws + b);
                if (tid < 256) {
                    float2 v = ldb2(p.wc_ws + (size_t)b * Hh + (tid << 1));
                    vL[(tid << 1)] = v.x; vL[(tid << 1) + 1] = v.y;
                    u32 u = ldbu(p.hyB + b * 256 + tid);
                    vL[512 + (tid << 1)] = bflo(u); vL[512 + (tid << 1) + 1] = bfhi(u);
                }
                __syncthreads();
                const float inv = invL[0];
                vL[tid] *= inv;                 // tid 0..511 = exactly the wc half
                __syncthreads();
                const int ko = tid >> 5;        // 0..15 (64-row K chunks)
                const int jp = tid & 31;        // col pair
                const int n0 = (cc << 6) + (jp << 1);
                size_t wi = wOffAo + ((size_t)(ko << 6)) * Hh + n0;
                const float* vr = vL + (ko << 6);
                float a0 = 0.f, a1 = 0.f;
                #pragma unroll 8
                for (int k = 0; k < 64; ++k) {
                    u32 u = *(const u32*)(p.waoB + wi);
                    a0 += vr[k] * bflo(u); a1 += vr[k] * bfhi(u);
                    wi += Hh;
                }
                red[ko * 68 + (jp << 1)] = a0; red[ko * 68 + (jp << 1) + 1] = a1;
                __syncthreads();
                if (tid < 64) {
                    float s = 0.f;
                    #pragma unroll
                    for (int q = 0; q < 16; ++q) s += red[q * 68 + tid];
                    float th = tanhf(s);
                    const int n2 = (cc << 6) + tid;
                    float oth = __shfl_xor(th, 1);
                    if (l == 0) {
                        // bypass pair store: layer-1 reads this cross-XCD, coherent by construction
                        if (!(tid & 1)) stout2b<F32>(p.out, xrow + n2, th, oth);
                    } else {
                        stout<F32>(p.out, xrow + n2, th);
                    }
                    if (last) stout<F32>(p.out, offH1 + (size_t)b * Hh + n2, th);
                    if (!(tid & 1))
                        stbu(p.hB + b * 256 + (cc << 5) + (tid >> 1), pack2bf(th, oth));
                    if (writeAtt) {
                        float pv = ldb(p.e_ws + (size_t)b * Ss + n2) * inv;
                        stout<F32>(p.out, offAtt + (size_t)n2 * (Tt * Bb) + (size_t)t * Bb + b, pv);
                    }
                }
            }
            bbar(ctr, (++ep) << 3);
        }
    }
}

__global__ __launch_bounds__(512, 2) void kmain(KP p) {
    __shared__ float smem[SMEM_FLOATS];
    if (*p.flag) run_all<true >(p, smem);
    else         run_all<false>(p, smem);
}

// ===========================================================================
// Fallback path: original per-timestep kernels (proven correct)
// ===========================================================================
template<bool F32>
__device__ __forceinline__ void gates_body(
    const void* xsrc, const void* h0, const void* c0,
    const void* Wi, const void* bi, const void* Wh, const void* bh,
    size_t wOff, size_t bOff,
    const float* h_ws, float* c_ws, float* hy_ws,
    void* out, unsigned long long offC1, int t, int writeC1)
{
    __shared__ float xh[1024];
    __shared__ float red[4][32][8];
    __shared__ float ga[4][32];

    const int b  = blockIdx.x >> 4;
    const int jc = blockIdx.x & 15;
    const int tid = threadIdx.x;

    const size_t xrow = ((size_t)b * Tt + t) * Hh;
    for (int i = tid; i < 512; i += 256) xh[i] = ldin<F32>(xsrc, xrow + i);
    if (t == 0) {
        for (int i = tid; i < 512; i += 256) xh[512 + i] = ldin<F32>(h0, (size_t)b * Hh + i);
    } else {
        for (int i = tid; i < 512; i += 256) xh[512 + i] = h_ws[b * Hh + i];
    }
    __syncthreads();

    const int jl = tid & 31;
    const int kq = tid >> 5;
    const int j  = jc * 32 + jl;
    const void* Wbase = (kq < 4) ? Wi : Wh;
    const int k0 = (kq & 3) * 128;
    const int xoff = (kq < 4) ? 0 : 512;

    float a0 = 0.f, a1 = 0.f, a2 = 0.f, a3 = 0.f;
    size_t widx = wOff + (size_t)k0 * G4H + j;
    #pragma unroll 4
    for (int k = 0; k < 128; ++k) {
        float xv = xh[xoff + k0 + k];
        a0 += xv * ldin<F32>(Wbase, widx + 0 * Hh);
        a1 += xv * ldin<F32>(Wbase, widx + 1 * Hh);
        a2 += xv * ldin<F32>(Wbase, widx + 2 * Hh);
        a3 += xv * ldin<F32>(Wbase, widx + 3 * Hh);
        widx += G4H;
    }
    red[0][jl][kq] = a0; red[1][jl][kq] = a1;
    red[2][jl][kq] = a2; red[3][jl][kq] = a3;
    __syncthreads();

    if (tid < 128) {
        int g = tid >> 5, jj = tid & 31;
        float s = 0.f;
        #pragma unroll
        for (int q = 0; q < 8; ++q) s += red[g][jj][q];
        ga[g][jj] = s;
    }
    __syncthreads();

    if (tid < 32) {
        int jj = tid;
        int n = jc * 32 + jj;
        float gi = ga[0][jj] + ldin<F32>(bi, bOff + 0 * Hh + n) + ldin<F32>(bh, bOff + 0 * Hh + n);
        float gf = ga[1][jj] + ldin<F32>(bi, bOff + 1 * Hh + n) + ldin<F32>(bh, bOff + 1 * Hh + n);
        float gg = ga[2][jj] + ldin<F32>(bi, bOff + 2 * Hh + n) + ldin<F32>(bh, bOff + 2 * Hh + n);
        float go = ga[3][jj] + ldin<F32>(bi, bOff + 3 * Hh + n) + ldin<F32>(bh, bOff + 3 * Hh + n);
        float ig = 1.f / (1.f + __expf(-gi));
        float fg = 1.f / (1.f + __expf(-gf));
        float g2 = tanhf(gg);
        float og = 1.f / (1.f + __expf(-go));
        float cp = (t == 0) ? ldin<F32>(c0, (size_t)b * Hh + n) : c_ws[b * Hh + n];
        float cy = fg * cp + ig * g2;
        float hy = og * tanhf(cy);
        c_ws[b * Hh + n]  = cy;
        hy_ws[b * Hh + n] = hy;
        if (writeC1) stout<F32>(out, offC1 + (size_t)b * Hh + n, cy);
    }
}

__global__ __launch_bounds__(256) void k_gates(
    const int* flag, const void* xsrc, const void* h0, const void* c0,
    const void* Wi, const void* bi, const void* Wh, const void* bh,
    unsigned long long wOff, unsigned long long bOff,
    const float* h_ws, float* c_ws, float* hy_ws,
    void* out, unsigned long long offC1, int t, int writeC1)
{
    if (*flag) gates_body<true >(xsrc, h0, c0, Wi, bi, Wh, bh, wOff, bOff, h_ws, c_ws, hy_ws, out, offC1, t, writeC1);
    else       gates_body<false>(xsrc, h0, c0, Wi, bi, Wh, bh, wOff, bOff, h_ws, c_ws, hy_ws, out, offC1, t, writeC1);
}

template<bool F32>
__device__ __forceinline__ void target_body(
    const float* hy_ws, const void* Wa_in, size_t wOff, float* tgt_ws)
{
    __shared__ float hyL[512];
    __shared__ float red[64][4];

    const int b  = blockIdx.x >> 3;
    const int nc = blockIdx.x & 7;
    const int tid = threadIdx.x;

    for (int i = tid; i < 512; i += 256) hyL[i] = hy_ws[b * Hh + i];
    __syncthreads();

    const int nl = tid & 63;
    const int kq = tid >> 6;
    const int n  = nc * 64 + nl;
    const int kb = kq * 128;
    float acc = 0.f;
    #pragma unroll 4
    for (int k = 0; k < 128; ++k)
        acc += hyL[kb + k] * ldin<F32>(Wa_in, wOff + (size_t)(kb + k) * Hh + n);
    red[nl][kq] = acc;
    __syncthreads();

    if (tid < 64) {
        float s = red[tid][0] + red[tid][1] + red[tid][2] + red[tid][3];
        tgt_ws[b * Hh + nc * 64 + tid] = s;
    }
}

__global__ __launch_bounds__(256) void k_target(
    const int* flag, const float* hy_ws, const void* Wa_in,
    unsigned long long wOff, float* tgt_ws)
{
    if (*flag) target_body<true >(hy_ws, Wa_in, wOff, tgt_ws);
    else       target_body<false>(hy_ws, Wa_in, wOff, tgt_ws);
}

template<bool F32>
__device__ __forceinline__ void scores_body(
    const void* ctx, const float* tgt_ws, float* sc_ws)
{
    const int w    = threadIdx.x >> 6;
    const int lane = threadIdx.x & 63;
    const int id = blockIdx.x * 4 + w;
    const int b = id & 31;
    const int s = id >> 5;

    const size_t base = ((size_t)s * Bb + b) * Hh + lane * 8;
    const float* tp = tgt_ws + (size_t)b * Hh + lane * 8;
    float d = 0.f;
    #pragma unroll
    for (int i = 0; i < 8; ++i) d += ldin<F32>(ctx, base + i) * tp[i];
    #pragma unroll
    for (int o = 32; o > 0; o >>= 1) d += __shfl_xor(d, o);
    if (lane == 0) sc_ws[b * Ss + s] = d;
}

__global__ __launch_bounds__(256) void k_scores(
    const int* flag, const void* ctx, const float* tgt_ws, float* sc_ws)
{
    if (*flag) scores_body<true >(ctx, tgt_ws, sc_ws);
    else       scores_body<false>(ctx, tgt_ws, sc_ws);
}

template<bool F32>
__device__ __forceinline__ void wc_body(
    const void* ctx, const float* sc_ws, float* wc_ws,
    void* out, unsigned long long offAtt, int t, int writeAtt)
{
    __shared__ float scL[512];
    __shared__ float red[256];

    const int b   = blockIdx.x >> 2;
    const int hc  = blockIdx.x & 3;
    const int tid = threadIdx.x;

    scL[tid]       = sc_ws[b * Ss + tid];
    scL[tid + 256] = sc_ws[b * Ss + tid + 256];
    __syncthreads();

    red[tid] = fmaxf(scL[tid], scL[tid + 256]);
    __syncthreads();
    for (int o = 128; o > 0; o >>= 1) {
        if (tid < o) red[tid] = fmaxf(red[tid], red[tid + o]);
        __syncthreads();
    }
    const float M = red[0];
    __syncthreads();

    red[tid] = __expf(scL[tid] - M) + __expf(scL[tid + 256] - M);
    __syncthreads();
    for (int o = 128; o > 0; o >>= 1) {
        if (tid < o) red[tid] += red[tid + o];
        __syncthreads();
    }
    const float inv = 1.f / red[0];
    __syncthreads();

    const int h    = hc * 128 + (tid & 127);
    const int half = tid >> 7;
    float acc = 0.f;
    const int s0 = half * 256;
    for (int s = s0; s < s0 + 256; ++s)
        acc += __expf(scL[s] - M) * ldin<F32>(ctx, ((size_t)s * Bb + b) * Hh + h);

    red[tid] = acc;
    __syncthreads();
    if (half == 0)
        wc_ws[b * Hh + h] = (red[tid] + red[tid + 128]) * inv;

    if (writeAtt && hc == 0) {
        float p0 = __expf(scL[tid] - M) * inv;
        float p1 = __expf(scL[tid + 256] - M) * inv;
        stout<F32>(out, offAtt + (size_t)tid         * (Tt * Bb) + (size_t)t * Bb + b, p0);
        stout<F32>(out, offAtt + (size_t)(tid + 256) * (Tt * Bb) + (size_t)t * Bb + b, p1);
    }
}

__global__ __launch_bounds__(256) void k_wc(
    const int* flag, const void* ctx, const float* sc_ws, float* wc_ws,
    void* out, unsigned long long offAtt, int t, int writeAtt)
{
    if (*flag) wc_body<true >(ctx, sc_ws, wc_ws, out, offAtt, t, writeAtt);
    else       wc_body<false>(ctx, sc_ws, wc_ws, out, offAtt, t, writeAtt);
}

template<bool F32>
__device__ __forceinline__ void out_body(
    const float* hy_ws, const float* wc_ws, const void* Wa_out, size_t wOff,
    float* h_ws, void* out, unsigned long long offH1, int t, int writeH1)
{
    __shared__ float vL[1024];
    __shared__ float red[32][8];

    const int b  = blockIdx.x >> 4;
    const int nc = blockIdx.x & 15;
    const int tid = threadIdx.x;

    for (int h = tid; h < 512; h += 256) {
        vL[h]       = wc_ws[b * Hh + h];
        vL[512 + h] = hy_ws[b * Hh + h];
    }
    __syncthreads();

    const int nl = tid & 31;
    const int kq = tid >> 5;
    const int n  = nc * 32 + nl;
    const int kb = kq * 128;
    float acc = 0.f;
    #pragma unroll 4
    for (int k = 0; k < 128; ++k)
        acc += vL[kb + k] * ldin<F32>(Wa_out, wOff + (size_t)(kb + k) * Hh + n);
    red[nl][kq] = acc;
    __syncthreads();

    if (tid < 32) {
        float s = 0.f;
        #pragma unroll
        for (int q = 0; q < 8; ++q) s += red[tid][q];
        float th = tanhf(s);
        int n2 = nc * 32 + tid;
        h_ws[b * Hh + n2] = th;
        stout<F32>(out, ((size_t)b * Tt + t) * Hh + n2, th);
        if (writeH1) stout<F32>(out, offH1 + (size_t)b * Hh + n2, th);
    }
}

__global__ __launch_bounds__(256) void k_out(
    const int* flag, const float* hy_ws, const float* wc_ws, const void* Wa_out,
    unsigned long long wOff, float* h_ws, void* out,
    unsigned long long offH1, int t, int writeH1)
{
    if (*flag) out_body<true >(hy_ws, wc_ws, Wa_out, wOff, h_ws, out, offH1, t, writeH1);
    else       out_body<false>(hy_ws, wc_ws, Wa_out, wOff, h_ws, out, offH1, t, writeH1);
}

// ---------------------------------------------------------------------------
extern "C" void kernel_launch(void* const* d_in, const int* in_sizes, int n_in,
                              void* d_out, int out_size, void* d_ws, size_t ws_size,
                              hipStream_t stream)
{
    const void* input  = d_in[0];
    const void* h0     = d_in[1];
    const void* c0     = d_in[2];
    const void* ctx    = d_in[3];
    const void* Wi     = d_in[4];
    const void* bi     = d_in[5];
    const void* Wh     = d_in[6];
    const void* bh     = d_in[7];
    const void* Wa_in  = d_in[8];
    const void* Wa_out = d_in[9];

    const size_t XN = (size_t)Bb * Tt * Hh;
    const size_t HN = (size_t)Bb * Hh;
    const unsigned long long offH1base = XN;
    const unsigned long long offC1base = XN + 2 * HN;
    const unsigned long long offAtt    = XN + 4 * HN;

    char* base = (char*)d_ws;
    int* flag  = (int*)base;
    int* bbars = (int*)(base + 128);                   // 32 groups x 64 ints
    float* f   = (float*)(base + 128 + 32 * 64 * 4);
    float* h_ws    = f; f += HN;                       // fallback only
    float* c_ws    = f; f += HN;                       // fallback only
    float* hy_ws   = f; f += HN;                       // fallback only
    float* tgt_ws  = f; f += HN;                       // fallback only
    float* wc_ws   = f; f += HN;
    float* e_ws    = f; f += (size_t)Bb * Ss;
    float* sc_ws   = f; f += (size_t)Bb * Ss;          // fallback only
    float* esum_ws = f; f += 64;

    size_t off = ((size_t)((char*)f - base) + 255) & ~(size_t)255;
    u32* hB   = (u32*)(base + off); off += 32 * 256 * 4;
    u32* hyB  = (u32*)(base + off); off += 32 * 256 * 4;
    off = (off + 255) & ~(size_t)255;
    const size_t NWI  = (size_t)2 * 512 * 2048;
    const size_t NWH  = (size_t)2 * 512 * 2048;
    const size_t NWAI = (size_t)2 * 512 * 512;
    const size_t NWAO = (size_t)2 * 1024 * 512;
    u16* wiB  = (u16*)(base + off); off += NWI * 2;
    u16* whB  = (u16*)(base + off); off += NWH * 2;
    u16* waiB = (u16*)(base + off); off += NWAI * 2;
    u16* waoB = (u16*)(base + off); off += NWAO * 2;
    const int fits = (ws_size >= off) ? 1 : 0;

    k_detect<<<dim3(1), dim3(256), 0, stream>>>(ctx, flag, bbars);

    hipError_t err = hipErrorUnknown;
    if (fits) {
        k_cvt<<<dim3((unsigned)(NWI  / 2048)), dim3(256), 0, stream>>>(flag, Wi,     wiB);
        k_cvt<<<dim3((unsigned)(NWH  / 2048)), dim3(256), 0, stream>>>(flag, Wh,     whB);
        k_cvt<<<dim3((unsigned)(NWAI / 2048)), dim3(256), 0, stream>>>(flag, Wa_in,  waiB);
        k_cvt<<<dim3((unsigned)(NWAO / 2048)), dim3(256), 0, stream>>>(flag, Wa_out, waoB);

        KP hp;
        hp.input = input; hp.h0 = h0; hp.c0 = c0; hp.ctx = ctx;
        hp.bi = bi; hp.bhp = bh;
        hp.wiB = wiB; hp.whB = whB; hp.waiB = waiB; hp.waoB = waoB;
        hp.out = d_out; hp.flag = flag; hp.bbars = bbars;
        hp.hB = hB; hp.hyB = hyB;
        hp.wc_ws = wc_ws; hp.e_ws = e_ws; hp.esum_ws = esum_ws;

        void* kargs[] = { &hp };
        err = hipLaunchCooperativeKernel(kmain, dim3(NBLK), dim3(512), kargs, 0u, stream);
    }

    if (err != hipSuccess) {
        (void)hipGetLastError();   // clear error state
        // Fallback: proven per-timestep multi-kernel path
        for (int l = 0; l < 2; ++l) {
            const void* xsrc = (l == 0) ? input : (const void*)d_out;
            const unsigned long long wOffG  = (unsigned long long)l * Hh * G4H;
            const unsigned long long bOffG  = (unsigned long long)l * G4H;
            const unsigned long long wOffAi = (unsigned long long)l * Hh * Hh;
            const unsigned long long wOffAo = (unsigned long long)l * 2 * Hh * Hh;
            const unsigned long long offH1  = offH1base + (unsigned long long)l * HN;
            const unsigned long long offC1  = offC1base + (unsigned long long)l * HN;

            for (int t = 0; t < Tt; ++t) {
                const int last = (t == Tt - 1) ? 1 : 0;
                k_gates<<<dim3(512), dim3(256), 0, stream>>>(
                    flag, xsrc, h0, c0, Wi, bi, Wh, bh, wOffG, bOffG,
                    h_ws, c_ws, hy_ws, d_out, offC1, t, last);
                k_target<<<dim3(256), dim3(256), 0, stream>>>(
                    flag, hy_ws, Wa_in, wOffAi, tgt_ws);
                k_scores<<<dim3(4096), dim3(256), 0, stream>>>(
                    flag, ctx, tgt_ws, sc_ws);
                k_wc<<<dim3(128), dim3(256), 0, stream>>>(
                    flag, ctx, sc_ws, wc_ws, d_out, offAtt, t, l);
                k_out<<<dim3(512), dim3(256), 0, stream>>>(
                    flag, hy_ws, wc_ws, Wa_out, wOffAo, h_ws, d_out, offH1, t, last);
            }
        }
    }
}

// Round 10
// 11600.038 us; speedup vs baseline: 2.4488x; 1.2178x over previous
//
#include <hip/hip_runtime.h>

typedef unsigned short u16;
typedef unsigned int   u32;
typedef unsigned long long u64;

#define Bb   32
#define Tt   256
#define Ss   512
#define Hh   512
#define G4H  2048
#define NBLK 256

// ---- dtype-polymorphic load/store: F32 ? fp32 : bf16 ------------------------
template<bool F32>
__device__ __forceinline__ float ldin(const void* p, size_t i) {
    if constexpr (F32) {
        return ((const float*)p)[i];
    } else {
        u32 v = ((u32)((const u16*)p)[i]) << 16;
        return __uint_as_float(v);
    }
}
template<bool F32>
__device__ __forceinline__ void stout(void* p, size_t i, float f) {
    if constexpr (F32) {
        ((float*)p)[i] = f;
    } else {
        u32 x = __float_as_uint(f);
        u32 r = x + 0x7fffu + ((x >> 16) & 1u);   // RNE
        ((u16*)p)[i] = (u16)(r >> 16);
    }
}
template<bool F32>
__device__ __forceinline__ float4 ld4(const void* p, size_t i) {
    if constexpr (F32) {
        return *(const float4*)((const float*)p + i);
    } else {
        ushort4 u = *(const ushort4*)((const u16*)p + i);
        float4 f;
        f.x = __uint_as_float((u32)u.x << 16);
        f.y = __uint_as_float((u32)u.y << 16);
        f.z = __uint_as_float((u32)u.z << 16);
        f.w = __uint_as_float((u32)u.w << 16);
        return f;
    }
}
__device__ __forceinline__ u32 pack2bf(float a, float b) {
    u32 xa = __float_as_uint(a), xb = __float_as_uint(b);
    u32 ra = (xa + 0x7fffu + ((xa >> 16) & 1u)) >> 16;
    u32 rb = (xb + 0x7fffu + ((xb >> 16) & 1u)) & 0xffff0000u;
    return ra | rb;
}
__device__ __forceinline__ float bflo(u32 u) { return __uint_as_float(u << 16); }
__device__ __forceinline__ float bfhi(u32 u) { return __uint_as_float(u & 0xffff0000u); }

// ---- cache-bypassing (coherence-point) accessors for mutable shared state ---
__device__ __forceinline__ float ldb(const float* p) {
    return __hip_atomic_load(p, __ATOMIC_RELAXED, __HIP_MEMORY_SCOPE_AGENT);
}
__device__ __forceinline__ void stb(float* p, float v) {
    __hip_atomic_store(p, v, __ATOMIC_RELAXED, __HIP_MEMORY_SCOPE_AGENT);
}
__device__ __forceinline__ float2 ldb2(const float* p) {
    u64 v = __hip_atomic_load((const u64*)p, __ATOMIC_RELAXED, __HIP_MEMORY_SCOPE_AGENT);
    float2 r;
    r.x = __uint_as_float((u32)v);
    r.y = __uint_as_float((u32)(v >> 32));
    return r;
}
__device__ __forceinline__ void stb2(float* p, float a, float b) {
    u64 v = (u64)__float_as_uint(a) | ((u64)__float_as_uint(b) << 32);
    __hip_atomic_store((u64*)p, v, __ATOMIC_RELAXED, __HIP_MEMORY_SCOPE_AGENT);
}
__device__ __forceinline__ u32 ldbu(const u32* p) {
    return __hip_atomic_load(p, __ATOMIC_RELAXED, __HIP_MEMORY_SCOPE_AGENT);
}
__device__ __forceinline__ void stbu(u32* p, u32 v) {
    __hip_atomic_store(p, v, __ATOMIC_RELAXED, __HIP_MEMORY_SCOPE_AGENT);
}
// bypass pair-store into the output buffer (layer-0 x handoff; no fences needed)
template<bool F32>
__device__ __forceinline__ void stout2b(void* p, size_t i, float a, float b) {
    if constexpr (F32) {
        stb2((float*)p + i, a, b);
    } else {
        stbu((u32*)p + (i >> 1), pack2bf(a, b));
    }
}

// ---- per-b-group barrier: 8 blocks (one per XCD), monotonic counter ---------
__device__ __forceinline__ void bbar(int* ctr, int target) {
    __syncthreads();
    if (threadIdx.x == 0) {
        asm volatile("s_waitcnt vmcnt(0)" ::: "memory");
        __hip_atomic_fetch_add(ctr, 1, __ATOMIC_RELAXED, __HIP_MEMORY_SCOPE_AGENT);
        while (__hip_atomic_load(ctr, __ATOMIC_RELAXED, __HIP_MEMORY_SCOPE_AGENT) < target)
            __builtin_amdgcn_s_sleep(1);
    }
    __syncthreads();
}

// ---------------------------------------------------------------------------
// K0: dtype detector + barrier-state init
// ---------------------------------------------------------------------------
__global__ __launch_bounds__(256) void k_detect(const void* ctx, int* flag, int* bbars) {
    __shared__ int c_sh;
    if (threadIdx.x == 0) c_sh = 0;
    __syncthreads();
    const u16* p = (const u16*)ctx;
    int c = 0;
    for (int i = threadIdx.x; i < 16384; i += 256) {
        int e = (p[i] >> 7) & 0xFF;
        if (e >= 0xC8) c++;
    }
    atomicAdd(&c_sh, c);
    __syncthreads();
    if (threadIdx.x == 0) *flag = (c_sh > 64) ? 1 : 0;
    if (threadIdx.x < 32) bbars[threadIdx.x * 64] = 0;
}

// ---------------------------------------------------------------------------
// K0b: generic -> bf16 conversion (copy-through if already bf16).
// ---------------------------------------------------------------------------
__global__ __launch_bounds__(256) void k_cvt(const int* flag, const void* src, u16* dst) {
    const size_t i = ((size_t)blockIdx.x * 256 + threadIdx.x) * 8;
    if (*flag) {
        const float* s = (const float*)src + i;
        float4 v0 = *(const float4*)(s);
        float4 v1 = *(const float4*)(s + 4);
        uint4 o;
        o.x = pack2bf(v0.x, v0.y);
        o.y = pack2bf(v0.z, v0.w);
        o.z = pack2bf(v1.x, v1.y);
        o.w = pack2bf(v1.z, v1.w);
        *(uint4*)(dst + i) = o;
    } else {
        *(uint4*)(dst + i) = *(const uint4*)((const u16*)src + i);
    }
}

// ===========================================================================
// Fused persistent kernel: 256 blocks x 1024 threads (16 waves/CU)
//  - fixed block identity (b = bid>>3, j = bid&7); XCD = j for all phases
//  - weights bf16, per-XCD slices CONTIGUOUS -> L2-resident (R7-proven)
//  - 3 phases/ts (R8 structure); P3 score/wc = R8-verbatim under tid<512
//  - per-b 8-block barriers; layer-0 x handoff via bypass stores
// ===========================================================================
struct KP {
    const void *input, *h0, *c0, *ctx, *bi, *bhp;
    const u16 *wiB, *whB, *waiB, *waoB;
    void* out;
    const int* flag;
    int* bbars;
    u32 *hB, *hyB;
    float *wc_ws, *e_ws, *esum_ws;
};

#define CTXU_FLOATS 16896     // 64 rows x 264 u32 (skewed bf16 pairs)
#define SCR_FLOATS  5504      // P1: 1024+4224+256 ; P3: 512+2080+528+64=3184 ; P4: 3201
#define SMEM_FLOATS (CTXU_FLOATS + SCR_FLOATS + 64)

template<bool F32>
__device__ void run_all(const KP& p, float* smem) {
    const int bid = blockIdx.x;
    const int tid = threadIdx.x;
    const int b  = bid >> 3;
    const int j8 = bid & 7;           // cc for P1/P4, sg for P3
    const size_t XN = (size_t)Bb * Tt * Hh;
    const size_t HN = (size_t)Bb * Hh;
    u32*   ctxU = (u32*)smem;
    float* S    = smem + CTXU_FLOATS;
    float* cL   = smem + CTXU_FLOATS + SCR_FLOATS;   // 64 floats, persistent
    int*   ctr  = p.bbars + b * 64;
    int ep = 0;

    // ---- one-time: stage ctx slice (b, sg=j8) into LDS (bf16-packed, skewed)
    for (int idx = tid; idx < 8192; idx += 1024) {
        const int r = idx >> 7, q4 = (idx & 127) << 2;
        float4 v = ld4<F32>(p.ctx, ((size_t)((j8 << 6) + r) * Bb + b) * Hh + q4);
        const int w = q4 >> 1;
        const int sk = w >> 5;
        ctxU[r * 264 + w + sk]     = pack2bf(v.x, v.y);
        ctxU[r * 264 + w + 1 + sk] = pack2bf(v.z, v.w);
    }
    __syncthreads();

    for (int l = 0; l < 2; ++l) {
        const size_t wOffG  = (size_t)l * Hh * G4H;
        const size_t bOffG  = (size_t)l * G4H;
        const size_t wOffAi = (size_t)l * Hh * Hh;
        const size_t wOffAo = (size_t)l * 2 * Hh * Hh;
        const size_t offH1  = XN + (size_t)l * HN;
        const size_t offC1  = XN + 2 * HN + (size_t)l * HN;
        const size_t offAtt = XN + 4 * HN;
        const int writeAtt = l;

        for (int t = 0; t < Tt; ++t) {
            const int last = (t == Tt - 1);
            const size_t xrow = ((size_t)b * Tt + t) * Hh;

            { // ---- P1: gates -> hy, cy.  block = (b, cc): 64 cols, K=1024, 16 chunks ----
                const int cc = j8;
                float* xh  = S;                 // 1024
                float* red = S + 1024;          // [16][264]
                float* ga  = S + 1024 + 4224;   // 256
                // stage x
                if (l == 0) {
                    if (tid < 128) {
                        float4 v = ld4<F32>(p.input, xrow + (tid << 2));
                        float* d = xh + (tid << 2);
                        d[0] = v.x; d[1] = v.y; d[2] = v.z; d[3] = v.w;
                    }
                } else {
                    if (tid < 256) {
                        if constexpr (F32) {
                            float2 v = ldb2((const float*)p.out + xrow + (tid << 1));
                            xh[(tid << 1)] = v.x; xh[(tid << 1) + 1] = v.y;
                        } else {
                            u32 u = ldbu((const u32*)p.out + (xrow >> 1) + tid);
                            xh[(tid << 1)] = bflo(u); xh[(tid << 1) + 1] = bfhi(u);
                        }
                    }
                }
                // stage h
                if (t == 0) {
                    if (tid < 128) {
                        float4 v = ld4<F32>(p.h0, (size_t)b * Hh + (tid << 2));
                        float* d = xh + 512 + (tid << 2);
                        d[0] = v.x; d[1] = v.y; d[2] = v.z; d[3] = v.w;
                    }
                } else {
                    if (tid < 256) {
                        u32 u = ldbu(p.hB + b * 256 + tid);
                        xh[512 + (tid << 1)] = bflo(u); xh[512 + (tid << 1) + 1] = bfhi(u);
                    }
                }
                // zero wc / esum for this timestep
                if (cc == 0) {
                    if (tid < 512) stb(p.wc_ws + (size_t)b * Hh + tid, 0.f);
                    if (tid == 0) stb(p.esum_ws + b, 0.f);
                }
                __syncthreads();

                const int kq  = tid >> 6;       // 0..15 (K chunk of 64; <8 -> Wi)
                const int rem = tid & 63;
                const int g   = rem >> 4;       // gate 0..3
                const int j4  = rem & 15;       // 4 cols
                const u16* Wb = (kq < 8) ? p.wiB : p.whB;
                size_t wi = wOffG + ((size_t)((kq & 7) << 6)) * G4H
                          + (size_t)((g << 9) + (cc << 6) + (j4 << 2));
                const float* xr = xh + (kq << 6);    // kq*64: x then h, contiguous
                float a0 = 0.f, a1 = 0.f, a2 = 0.f, a3 = 0.f;
                #pragma unroll 8
                for (int k = 0; k < 64; ++k) {
                    float4 w = ld4<false>(Wb, wi);
                    float xv = xr[k];
                    a0 += xv * w.x; a1 += xv * w.y; a2 += xv * w.z; a3 += xv * w.w;
                    wi += G4H;
                }
                float4 rv; rv.x = a0; rv.y = a1; rv.z = a2; rv.w = a3;
                *(float4*)(red + kq * 264 + (g << 6) + (j4 << 2)) = rv;
                __syncthreads();
                if (tid < 256) {
                    float s = 0.f;
                    #pragma unroll
                    for (int q = 0; q < 16; ++q) s += red[q * 264 + tid];
                    ga[tid] = s;
                }
                __syncthreads();
                if (tid < 64) {
                    const int j = tid;
                    const int n = (cc << 6) + j;
                    float gi = ga[j]        + ldin<F32>(p.bi, bOffG + n)        + ldin<F32>(p.bhp, bOffG + n);
                    float gf = ga[64 + j]   + ldin<F32>(p.bi, bOffG + 512 + n)  + ldin<F32>(p.bhp, bOffG + 512 + n);
                    float gg = ga[128 + j]  + ldin<F32>(p.bi, bOffG + 1024 + n) + ldin<F32>(p.bhp, bOffG + 1024 + n);
                    float go = ga[192 + j]  + ldin<F32>(p.bi, bOffG + 1536 + n) + ldin<F32>(p.bhp, bOffG + 1536 + n);
                    float ig = 1.f / (1.f + __expf(-gi));
                    float fg = 1.f / (1.f + __expf(-gf));
                    float g2 = tanhf(gg);
                    float og = 1.f / (1.f + __expf(-go));
                    float cp = (t == 0) ? ldin<F32>(p.c0, (size_t)b * Hh + n) : cL[j];
                    float cy = fg * cp + ig * g2;
                    float hy = og * tanhf(cy);
                    cL[j] = cy;
                    if (last) stout<F32>(p.out, offC1 + (size_t)b * Hh + n, cy);
                    float ohy = __shfl_xor(hy, 1);
                    if (!(j & 1))
                        stbu(p.hyB + b * 256 + (cc << 5) + (j >> 1), pack2bf(hy, ohy));
                }
            }
            bbar(ctr, (++ep) << 3);

            { // ---- P3: tgt-compute (4 chunks) + R8-verbatim scores/wc.  block = (b, sg) ----
                const int sg = j8;
                float* hyL  = S;                // 512
                float* red2 = S + 512;          // [4][520]
                float* tgtL = S + 2592;         // [8][66] skewed
                float* eL   = S + 3120;         // 64
                if (tid < 256) {
                    u32 u = ldbu(p.hyB + b * 256 + tid);
                    hyL[(tid << 1)] = bflo(u); hyL[(tid << 1) + 1] = bfhi(u);
                }
                __syncthreads();
                { // tgt = hy @ Wa_in (redundant per sg; Wa_in L2-resident), 4x128-row chunks
                    const int kh = tid >> 8, np = tid & 255;
                    const int n0 = np << 1;
                    size_t wi = wOffAi + ((size_t)(kh << 7)) * Hh + n0;
                    const float* hr = hyL + (kh << 7);
                    float a0 = 0.f, a1 = 0.f;
                    #pragma unroll 8
                    for (int k = 0; k < 128; ++k) {
                        u32 u = *(const u32*)(p.waiB + wi);
                        a0 += hr[k] * bflo(u); a1 += hr[k] * bfhi(u);
                        wi += Hh;
                    }
                    red2[kh * 520 + n0] = a0; red2[kh * 520 + n0 + 1] = a1;
                }
                __syncthreads();
                if (tid < 512)
                    tgtL[(tid >> 6) * 66 + (tid & 63)] =
                        red2[tid] + red2[520 + tid] + red2[1040 + tid] + red2[1560 + tid];
                __syncthreads();
                if (tid < 512) {    // R8-verbatim score computation
                    const int r = tid >> 3, kq = tid & 7;
                    const u32* cw = ctxU + r * 264 + kq * 33;
                    const float* tp = tgtL + kq * 66;
                    float d = 0.f;
                    #pragma unroll 8
                    for (int j = 0; j < 32; ++j) {
                        u32 u = cw[j];
                        d += __uint_as_float(u << 16)         * tp[2 * j]
                           + __uint_as_float(u & 0xffff0000u) * tp[2 * j + 1];
                    }
                    d += __shfl_xor(d, 1); d += __shfl_xor(d, 2); d += __shfl_xor(d, 4);
                    if (kq == 0) {
                        float e = __expf(d);    // bounded: |score| <~ 60, safe in fp32
                        eL[r] = e;
                        stb(p.e_ws + (size_t)b * Ss + (sg << 6) + r, e);
                    }
                }
                __syncthreads();
                if (tid < 64) {
                    float w = eL[tid];
                    #pragma unroll
                    for (int o = 32; o > 0; o >>= 1) w += __shfl_xor(w, o);
                    if (tid == 0) atomicAdd(p.esum_ws + b, w);
                }
                if (tid < 512) {    // R8-verbatim wc partials
                    const int wd = tid >> 1, hodd = tid & 1;
                    const int woff = wd + (wd >> 5);
                    float acc = 0.f;
                    #pragma unroll 8
                    for (int rr = 0; rr < 64; ++rr) {
                        u32 u = ctxU[rr * 264 + woff];
                        float v = hodd ? __uint_as_float(u & 0xffff0000u) : __uint_as_float(u << 16);
                        acc += eL[rr] * v;
                    }
                    atomicAdd(p.wc_ws + (size_t)b * Hh + tid, acc);
                }
            }
            bbar(ctr, (++ep) << 3);

            { // ---- P4: h~ = tanh([wc,hy]@Wa_out).  block = (b, cc): 64 cols, 32 chunks ----
                const int cc = j8;
                float* vL   = S;                // 1024
                float* red  = S + 1024;         // [32][68]
                float* invL = S + 1024 + 2176;  // 1
                if (tid == 0) invL[0] = 1.f / ldb(p.esum_ws + b);
                if (tid < 256) {
                    float2 v = ldb2(p.wc_ws + (size_t)b * Hh + (tid << 1));
                    vL[(tid << 1)] = v.x; vL[(tid << 1) + 1] = v.y;
                    u32 u = ldbu(p.hyB + b * 256 + tid);
                    vL[512 + (tid << 1)] = bflo(u); vL[512 + (tid << 1) + 1] = bfhi(u);
                }
                __syncthreads();
                const float inv = invL[0];
                if (tid < 512) vL[tid] *= inv;  // exactly the wc half
                __syncthreads();
                const int ko = tid >> 5;        // 0..31 (32-row K chunks)
                const int jp = tid & 31;        // col pair
                const int n0 = (cc << 6) + (jp << 1);
                size_t wi = wOffAo + ((size_t)(ko << 5)) * Hh + n0;
                const float* vr = vL + (ko << 5);
                float a0 = 0.f, a1 = 0.f;
                #pragma unroll 8
                for (int k = 0; k < 32; ++k) {
                    u32 u = *(const u32*)(p.waoB + wi);
                    a0 += vr[k] * bflo(u); a1 += vr[k] * bfhi(u);
                    wi += Hh;
                }
                red[ko * 68 + (jp << 1)] = a0; red[ko * 68 + (jp << 1) + 1] = a1;
                __syncthreads();
                if (tid < 64) {
                    float s = 0.f;
                    #pragma unroll
                    for (int q = 0; q < 32; ++q) s += red[q * 68 + tid];
                    float th = tanhf(s);
                    const int n2 = (cc << 6) + tid;
                    float oth = __shfl_xor(th, 1);
                    if (l == 0) {
                        // bypass pair store: layer-1 reads this cross-XCD, coherent by construction
                        if (!(tid & 1)) stout2b<F32>(p.out, xrow + n2, th, oth);
                    } else {
                        stout<F32>(p.out, xrow + n2, th);
                    }
                    if (last) stout<F32>(p.out, offH1 + (size_t)b * Hh + n2, th);
                    if (!(tid & 1))
                        stbu(p.hB + b * 256 + (cc << 5) + (tid >> 1), pack2bf(th, oth));
                    if (writeAtt) {
                        float pv = ldb(p.e_ws + (size_t)b * Ss + n2) * inv;
                        stout<F32>(p.out, offAtt + (size_t)n2 * (Tt * Bb) + (size_t)t * Bb + b, pv);
                    }
                }
            }
            bbar(ctr, (++ep) << 3);
        }
    }
}

__global__ __launch_bounds__(1024, 1) void kmain(KP p) {
    __shared__ float smem[SMEM_FLOATS];
    if (*p.flag) run_all<true >(p, smem);
    else         run_all<false>(p, smem);
}

// ===========================================================================
// Fallback path: original per-timestep kernels (proven correct)
// ===========================================================================
template<bool F32>
__device__ __forceinline__ void gates_body(
    const void* xsrc, const void* h0, const void* c0,
    const void* Wi, const void* bi, const void* Wh, const void* bh,
    size_t wOff, size_t bOff,
    const float* h_ws, float* c_ws, float* hy_ws,
    void* out, unsigned long long offC1, int t, int writeC1)
{
    __shared__ float xh[1024];
    __shared__ float red[4][32][8];
    __shared__ float ga[4][32];

    const int b  = blockIdx.x >> 4;
    const int jc = blockIdx.x & 15;
    const int tid = threadIdx.x;

    const size_t xrow = ((size_t)b * Tt + t) * Hh;
    for (int i = tid; i < 512; i += 256) xh[i] = ldin<F32>(xsrc, xrow + i);
    if (t == 0) {
        for (int i = tid; i < 512; i += 256) xh[512 + i] = ldin<F32>(h0, (size_t)b * Hh + i);
    } else {
        for (int i = tid; i < 512; i += 256) xh[512 + i] = h_ws[b * Hh + i];
    }
    __syncthreads();

    const int jl = tid & 31;
    const int kq = tid >> 5;
    const int j  = jc * 32 + jl;
    const void* Wbase = (kq < 4) ? Wi : Wh;
    const int k0 = (kq & 3) * 128;
    const int xoff = (kq < 4) ? 0 : 512;

    float a0 = 0.f, a1 = 0.f, a2 = 0.f, a3 = 0.f;
    size_t widx = wOff + (size_t)k0 * G4H + j;
    #pragma unroll 4
    for (int k = 0; k < 128; ++k) {
        float xv = xh[xoff + k0 + k];
        a0 += xv * ldin<F32>(Wbase, widx + 0 * Hh);
        a1 += xv * ldin<F32>(Wbase, widx + 1 * Hh);
        a2 += xv * ldin<F32>(Wbase, widx + 2 * Hh);
        a3 += xv * ldin<F32>(Wbase, widx + 3 * Hh);
        widx += G4H;
    }
    red[0][jl][kq] = a0; red[1][jl][kq] = a1;
    red[2][jl][kq] = a2; red[3][jl][kq] = a3;
    __syncthreads();

    if (tid < 128) {
        int g = tid >> 5, jj = tid & 31;
        float s = 0.f;
        #pragma unroll
        for (int q = 0; q < 8; ++q) s += red[g][jj][q];
        ga[g][jj] = s;
    }
    __syncthreads();

    if (tid < 32) {
        int jj = tid;
        int n = jc * 32 + jj;
        float gi = ga[0][jj] + ldin<F32>(bi, bOff + 0 * Hh + n) + ldin<F32>(bh, bOff + 0 * Hh + n);
        float gf = ga[1][jj] + ldin<F32>(bi, bOff + 1 * Hh + n) + ldin<F32>(bh, bOff + 1 * Hh + n);
        float gg = ga[2][jj] + ldin<F32>(bi, bOff + 2 * Hh + n) + ldin<F32>(bh, bOff + 2 * Hh + n);
        float go = ga[3][jj] + ldin<F32>(bi, bOff + 3 * Hh + n) + ldin<F32>(bh, bOff + 3 * Hh + n);
        float ig = 1.f / (1.f + __expf(-gi));
        float fg = 1.f / (1.f + __expf(-gf));
        float g2 = tanhf(gg);
        float og = 1.f / (1.f + __expf(-go));
        float cp = (t == 0) ? ldin<F32>(c0, (size_t)b * Hh + n) : c_ws[b * Hh + n];
        float cy = fg * cp + ig * g2;
        float hy = og * tanhf(cy);
        c_ws[b * Hh + n]  = cy;
        hy_ws[b * Hh + n] = hy;
        if (writeC1) stout<F32>(out, offC1 + (size_t)b * Hh + n, cy);
    }
}

__global__ __launch_bounds__(256) void k_gates(
    const int* flag, const void* xsrc, const void* h0, const void* c0,
    const void* Wi, const void* bi, const void* Wh, const void* bh,
    unsigned long long wOff, unsigned long long bOff,
    const float* h_ws, float* c_ws, float* hy_ws,
    void* out, unsigned long long offC1, int t, int writeC1)
{
    if (*flag) gates_body<true >(xsrc, h0, c0, Wi, bi, Wh, bh, wOff, bOff, h_ws, c_ws, hy_ws, out, offC1, t, writeC1);
    else       gates_body<false>(xsrc, h0, c0, Wi, bi, Wh, bh, wOff, bOff, h_ws, c_ws, hy_ws, out, offC1, t, writeC1);
}

template<bool F32>
__device__ __forceinline__ void target_body(
    const float* hy_ws, const void* Wa_in, size_t wOff, float* tgt_ws)
{
    __shared__ float hyL[512];
    __shared__ float red[64][4];

    const int b  = blockIdx.x >> 3;
    const int nc = blockIdx.x & 7;
    const int tid = threadIdx.x;

    for (int i = tid; i < 512; i += 256) hyL[i] = hy_ws[b * Hh + i];
    __syncthreads();

    const int nl = tid & 63;
    const int kq = tid >> 6;
    const int n  = nc * 64 + nl;
    const int kb = kq * 128;
    float acc = 0.f;
    #pragma unroll 4
    for (int k = 0; k < 128; ++k)
        acc += hyL[kb + k] * ldin<F32>(Wa_in, wOff + (size_t)(kb + k) * Hh + n);
    red[nl][kq] = acc;
    __syncthreads();

    if (tid < 64) {
        float s = red[tid][0] + red[tid][1] + red[tid][2] + red[tid][3];
        tgt_ws[b * Hh + nc * 64 + tid] = s;
    }
}

__global__ __launch_bounds__(256) void k_target(
    const int* flag, const float* hy_ws, const void* Wa_in,
    unsigned long long wOff, float* tgt_ws)
{
    if (*flag) target_body<true >(hy_ws, Wa_in, wOff, tgt_ws);
    else       target_body<false>(hy_ws, Wa_in, wOff, tgt_ws);
}

template<bool F32>
__device__ __forceinline__ void scores_body(
    const void* ctx, const float* tgt_ws, float* sc_ws)
{
    const int w    = threadIdx.x >> 6;
    const int lane = threadIdx.x & 63;
    const int id = blockIdx.x * 4 + w;
    const int b = id & 31;
    const int s = id >> 5;

    const size_t base = ((size_t)s * Bb + b) * Hh + lane * 8;
    const float* tp = tgt_ws + (size_t)b * Hh + lane * 8;
    float d = 0.f;
    #pragma unroll
    for (int i = 0; i < 8; ++i) d += ldin<F32>(ctx, base + i) * tp[i];
    #pragma unroll
    for (int o = 32; o > 0; o >>= 1) d += __shfl_xor(d, o);
    if (lane == 0) sc_ws[b * Ss + s] = d;
}

__global__ __launch_bounds__(256) void k_scores(
    const int* flag, const void* ctx, const float* tgt_ws, float* sc_ws)
{
    if (*flag) scores_body<true >(ctx, tgt_ws, sc_ws);
    else       scores_body<false>(ctx, tgt_ws, sc_ws);
}

template<bool F32>
__device__ __forceinline__ void wc_body(
    const void* ctx, const float* sc_ws, float* wc_ws,
    void* out, unsigned long long offAtt, int t, int writeAtt)
{
    __shared__ float scL[512];
    __shared__ float red[256];

    const int b   = blockIdx.x >> 2;
    const int hc  = blockIdx.x & 3;
    const int tid = threadIdx.x;

    scL[tid]       = sc_ws[b * Ss + tid];
    scL[tid + 256] = sc_ws[b * Ss + tid + 256];
    __syncthreads();

    red[tid] = fmaxf(scL[tid], scL[tid + 256]);
    __syncthreads();
    for (int o = 128; o > 0; o >>= 1) {
        if (tid < o) red[tid] = fmaxf(red[tid], red[tid + o]);
        __syncthreads();
    }
    const float M = red[0];
    __syncthreads();

    red[tid] = __expf(scL[tid] - M) + __expf(scL[tid + 256] - M);
    __syncthreads();
    for (int o = 128; o > 0; o >>= 1) {
        if (tid < o) red[tid] += red[tid + o];
        __syncthreads();
    }
    const float inv = 1.f / red[0];
    __syncthreads();

    const int h    = hc * 128 + (tid & 127);
    const int half = tid >> 7;
    float acc = 0.f;
    const int s0 = half * 256;
    for (int s = s0; s < s0 + 256; ++s)
        acc += __expf(scL[s] - M) * ldin<F32>(ctx, ((size_t)s * Bb + b) * Hh + h);

    red[tid] = acc;
    __syncthreads();
    if (half == 0)
        wc_ws[b * Hh + h] = (red[tid] + red[tid + 128]) * inv;

    if (writeAtt && hc == 0) {
        float p0 = __expf(scL[tid] - M) * inv;
        float p1 = __expf(scL[tid + 256] - M) * inv;
        stout<F32>(out, offAtt + (size_t)tid         * (Tt * Bb) + (size_t)t * Bb + b, p0);
        stout<F32>(out, offAtt + (size_t)(tid + 256) * (Tt * Bb) + (size_t)t * Bb + b, p1);
    }
}

__global__ __launch_bounds__(256) void k_wc(
    const int* flag, const void* ctx, const float* sc_ws, float* wc_ws,
    void* out, unsigned long long offAtt, int t, int writeAtt)
{
    if (*flag) wc_body<true >(ctx, sc_ws, wc_ws, out, offAtt, t, writeAtt);
    else       wc_body<false>(ctx, sc_ws, wc_ws, out, offAtt, t, writeAtt);
}

template<bool F32>
__device__ __forceinline__ void out_body(
    const float* hy_ws, const float* wc_ws, const void* Wa_out, size_t wOff,
    float* h_ws, void* out, unsigned long long offH1, int t, int writeH1)
{
    __shared__ float vL[1024];
    __shared__ float red[32][8];

    const int b  = blockIdx.x >> 4;
    const int nc = blockIdx.x & 15;
    const int tid = threadIdx.x;

    for (int h = tid; h < 512; h += 256) {
        vL[h]       = wc_ws[b * Hh + h];
        vL[512 + h] = hy_ws[b * Hh + h];
    }
    __syncthreads();

    const int nl = tid & 31;
    const int kq = tid >> 5;
    const int n  = nc * 32 + nl;
    const int kb = kq * 128;
    float acc = 0.f;
    #pragma unroll 4
    for (int k = 0; k < 128; ++k)
        acc += vL[kb + k] * ldin<F32>(Wa_out, wOff + (size_t)(kb + k) * Hh + n);
    red[nl][kq] = acc;
    __syncthreads();

    if (tid < 32) {
        float s = 0.f;
        #pragma unroll
        for (int q = 0; q < 8; ++q) s += red[tid][q];
        float th = tanhf(s);
        int n2 = nc * 32 + tid;
        h_ws[b * Hh + n2] = th;
        stout<F32>(out, ((size_t)b * Tt + t) * Hh + n2, th);
        if (writeH1) stout<F32>(out, offH1 + (size_t)b * Hh + n2, th);
    }
}

__global__ __launch_bounds__(256) void k_out(
    const int* flag, const float* hy_ws, const float* wc_ws, const void* Wa_out,
    unsigned long long wOff, float* h_ws, void* out,
    unsigned long long offH1, int t, int writeH1)
{
    if (*flag) out_body<true >(hy_ws, wc_ws, Wa_out, wOff, h_ws, out, offH1, t, writeH1);
    else       out_body<false>(hy_ws, wc_ws, Wa_out, wOff, h_ws, out, offH1, t, writeH1);
}

// ---------------------------------------------------------------------------
extern "C" void kernel_launch(void* const* d_in, const int* in_sizes, int n_in,
                              void* d_out, int out_size, void* d_ws, size_t ws_size,
                              hipStream_t stream)
{
    const void* input  = d_in[0];
    const void* h0     = d_in[1];
    const void* c0     = d_in[2];
    const void* ctx    = d_in[3];
    const void* Wi     = d_in[4];
    const void* bi     = d_in[5];
    const void* Wh     = d_in[6];
    const void* bh     = d_in[7];
    const void* Wa_in  = d_in[8];
    const void* Wa_out = d_in[9];

    const size_t XN = (size_t)Bb * Tt * Hh;
    const size_t HN = (size_t)Bb * Hh;
    const unsigned long long offH1base = XN;
    const unsigned long long offC1base = XN + 2 * HN;
    const unsigned long long offAtt    = XN + 4 * HN;

    char* base = (char*)d_ws;
    int* flag  = (int*)base;
    int* bbars = (int*)(base + 128);                   // 32 groups x 64 ints
    float* f   = (float*)(base + 128 + 32 * 64 * 4);
    float* h_ws    = f; f += HN;                       // fallback only
    float* c_ws    = f; f += HN;                       // fallback only
    float* hy_ws   = f; f += HN;                       // fallback only
    float* tgt_ws  = f; f += HN;                       // fallback only
    float* wc_ws   = f; f += HN;
    float* e_ws    = f; f += (size_t)Bb * Ss;
    float* sc_ws   = f; f += (size_t)Bb * Ss;          // fallback only
    float* esum_ws = f; f += 64;

    size_t off = ((size_t)((char*)f - base) + 255) & ~(size_t)255;
    u32* hB   = (u32*)(base + off); off += 32 * 256 * 4;
    u32* hyB  = (u32*)(base + off); off += 32 * 256 * 4;
    off = (off + 255) & ~(size_t)255;
    const size_t NWI  = (size_t)2 * 512 * 2048;
    const size_t NWH  = (size_t)2 * 512 * 2048;
    const size_t NWAI = (size_t)2 * 512 * 512;
    const size_t NWAO = (size_t)2 * 1024 * 512;
    u16* wiB  = (u16*)(base + off); off += NWI * 2;
    u16* whB  = (u16*)(base + off); off += NWH * 2;
    u16* waiB = (u16*)(base + off); off += NWAI * 2;
    u16* waoB = (u16*)(base + off); off += NWAO * 2;
    const int fits = (ws_size >= off) ? 1 : 0;

    k_detect<<<dim3(1), dim3(256), 0, stream>>>(ctx, flag, bbars);

    hipError_t err = hipErrorUnknown;
    if (fits) {
        k_cvt<<<dim3((unsigned)(NWI  / 2048)), dim3(256), 0, stream>>>(flag, Wi,     wiB);
        k_cvt<<<dim3((unsigned)(NWH  / 2048)), dim3(256), 0, stream>>>(flag, Wh,     whB);
        k_cvt<<<dim3((unsigned)(NWAI / 2048)), dim3(256), 0, stream>>>(flag, Wa_in,  waiB);
        k_cvt<<<dim3((unsigned)(NWAO / 2048)), dim3(256), 0, stream>>>(flag, Wa_out, waoB);

        KP hp;
        hp.input = input; hp.h0 = h0; hp.c0 = c0; hp.ctx = ctx;
        hp.bi = bi; hp.bhp = bh;
        hp.wiB = wiB; hp.whB = whB; hp.waiB = waiB; hp.waoB = waoB;
        hp.out = d_out; hp.flag = flag; hp.bbars = bbars;
        hp.hB = hB; hp.hyB = hyB;
        hp.wc_ws = wc_ws; hp.e_ws = e_ws; hp.esum_ws = esum_ws;

        void* kargs[] = { &hp };
        err = hipLaunchCooperativeKernel(kmain, dim3(NBLK), dim3(1024), kargs, 0u, stream);
    }

    if (err != hipSuccess) {
        (void)hipGetLastError();   // clear error state
        // Fallback: proven per-timestep multi-kernel path
        for (int l = 0; l < 2; ++l) {
            const void* xsrc = (l == 0) ? input : (const void*)d_out;
            const unsigned long long wOffG  = (unsigned long long)l * Hh * G4H;
            const unsigned long long bOffG  = (unsigned long long)l * G4H;
            const unsigned long long wOffAi = (unsigned long long)l * Hh * Hh;
            const unsigned long long wOffAo = (unsigned long long)l * 2 * Hh * Hh;
            const unsigned long long offH1  = offH1base + (unsigned long long)l * HN;
            const unsigned long long offC1  = offC1base + (unsigned long long)l * HN;

            for (int t = 0; t < Tt; ++t) {
                const int last = (t == Tt - 1) ? 1 : 0;
                k_gates<<<dim3(512), dim3(256), 0, stream>>>(
                    flag, xsrc, h0, c0, Wi, bi, Wh, bh, wOffG, bOffG,
                    h_ws, c_ws, hy_ws, d_out, offC1, t, last);
                k_target<<<dim3(256), dim3(256), 0, stream>>>(
                    flag, hy_ws, Wa_in, wOffAi, tgt_ws);
                k_scores<<<dim3(4096), dim3(256), 0, stream>>>(
                    flag, ctx, tgt_ws, sc_ws);
                k_wc<<<dim3(128), dim3(256), 0, stream>>>(
                    flag, ctx, sc_ws, wc_ws, d_out, offAtt, t, l);
                k_out<<<dim3(512), dim3(256), 0, stream>>>(
                    flag, hy_ws, wc_ws, Wa_out, wOffAo, h_ws, d_out, offH1, t, last);
            }
        }
    }
}

// Round 11
// 10749.948 us; speedup vs baseline: 2.6425x; 1.0791x over previous
//
#include <hip/hip_runtime.h>

typedef unsigned short u16;
typedef unsigned int   u32;
typedef unsigned long long u64;

#define Bb   32
#define Tt   256
#define Ss   512
#define Hh   512
#define G4H  2048
#define NBLK 256

// ---- dtype-polymorphic load/store: F32 ? fp32 : bf16 ------------------------
template<bool F32>
__device__ __forceinline__ float ldin(const void* p, size_t i) {
    if constexpr (F32) {
        return ((const float*)p)[i];
    } else {
        u32 v = ((u32)((const u16*)p)[i]) << 16;
        return __uint_as_float(v);
    }
}
template<bool F32>
__device__ __forceinline__ void stout(void* p, size_t i, float f) {
    if constexpr (F32) {
        ((float*)p)[i] = f;
    } else {
        u32 x = __float_as_uint(f);
        u32 r = x + 0x7fffu + ((x >> 16) & 1u);   // RNE
        ((u16*)p)[i] = (u16)(r >> 16);
    }
}
template<bool F32>
__device__ __forceinline__ float4 ld4(const void* p, size_t i) {
    if constexpr (F32) {
        return *(const float4*)((const float*)p + i);
    } else {
        ushort4 u = *(const ushort4*)((const u16*)p + i);
        float4 f;
        f.x = __uint_as_float((u32)u.x << 16);
        f.y = __uint_as_float((u32)u.y << 16);
        f.z = __uint_as_float((u32)u.z << 16);
        f.w = __uint_as_float((u32)u.w << 16);
        return f;
    }
}
__device__ __forceinline__ u32 pack2bf(float a, float b) {
    u32 xa = __float_as_uint(a), xb = __float_as_uint(b);
    u32 ra = (xa + 0x7fffu + ((xa >> 16) & 1u)) >> 16;
    u32 rb = (xb + 0x7fffu + ((xb >> 16) & 1u)) & 0xffff0000u;
    return ra | rb;
}
__device__ __forceinline__ float bflo(u32 u) { return __uint_as_float(u << 16); }
__device__ __forceinline__ float bfhi(u32 u) { return __uint_as_float(u & 0xffff0000u); }

// ---- cache-bypassing (coherence-point) accessors for mutable shared state ---
__device__ __forceinline__ float ldb(const float* p) {
    return __hip_atomic_load(p, __ATOMIC_RELAXED, __HIP_MEMORY_SCOPE_AGENT);
}
__device__ __forceinline__ void stb(float* p, float v) {
    __hip_atomic_store(p, v, __ATOMIC_RELAXED, __HIP_MEMORY_SCOPE_AGENT);
}
__device__ __forceinline__ float2 ldb2(const float* p) {
    u64 v = __hip_atomic_load((const u64*)p, __ATOMIC_RELAXED, __HIP_MEMORY_SCOPE_AGENT);
    float2 r;
    r.x = __uint_as_float((u32)v);
    r.y = __uint_as_float((u32)(v >> 32));
    return r;
}
__device__ __forceinline__ void stb2(float* p, float a, float b) {
    u64 v = (u64)__float_as_uint(a) | ((u64)__float_as_uint(b) << 32);
    __hip_atomic_store((u64*)p, v, __ATOMIC_RELAXED, __HIP_MEMORY_SCOPE_AGENT);
}
__device__ __forceinline__ u32 ldbu(const u32* p) {
    return __hip_atomic_load(p, __ATOMIC_RELAXED, __HIP_MEMORY_SCOPE_AGENT);
}
__device__ __forceinline__ void stbu(u32* p, u32 v) {
    __hip_atomic_store(p, v, __ATOMIC_RELAXED, __HIP_MEMORY_SCOPE_AGENT);
}
// bypass pair-store into the output buffer (layer-0 x handoff; no fences needed)
template<bool F32>
__device__ __forceinline__ void stout2b(void* p, size_t i, float a, float b) {
    if constexpr (F32) {
        stb2((float*)p + i, a, b);
    } else {
        stbu((u32*)p + (i >> 1), pack2bf(a, b));
    }
}

// ---- per-b-group barrier: 8 blocks (one per XCD), monotonic counter ---------
__device__ __forceinline__ void bbar(int* ctr, int target) {
    __syncthreads();
    if (threadIdx.x == 0) {
        asm volatile("s_waitcnt vmcnt(0)" ::: "memory");
        __hip_atomic_fetch_add(ctr, 1, __ATOMIC_RELAXED, __HIP_MEMORY_SCOPE_AGENT);
        while (__hip_atomic_load(ctr, __ATOMIC_RELAXED, __HIP_MEMORY_SCOPE_AGENT) < target)
            __builtin_amdgcn_s_sleep(1);
    }
    __syncthreads();
}

// ---------------------------------------------------------------------------
// K0: dtype detector + barrier-state init
// ---------------------------------------------------------------------------
__global__ __launch_bounds__(256) void k_detect(const void* ctx, int* flag, int* bbars) {
    __shared__ int c_sh;
    if (threadIdx.x == 0) c_sh = 0;
    __syncthreads();
    const u16* p = (const u16*)ctx;
    int c = 0;
    for (int i = threadIdx.x; i < 16384; i += 256) {
        int e = (p[i] >> 7) & 0xFF;
        if (e >= 0xC8) c++;
    }
    atomicAdd(&c_sh, c);
    __syncthreads();
    if (threadIdx.x == 0) *flag = (c_sh > 64) ? 1 : 0;
    if (threadIdx.x < 32) bbars[threadIdx.x * 64] = 0;
}

// ---------------------------------------------------------------------------
// K0b: generic -> bf16 conversion (copy-through if already bf16).
// ---------------------------------------------------------------------------
__global__ __launch_bounds__(256) void k_cvt(const int* flag, const void* src, u16* dst) {
    const size_t i = ((size_t)blockIdx.x * 256 + threadIdx.x) * 8;
    if (*flag) {
        const float* s = (const float*)src + i;
        float4 v0 = *(const float4*)(s);
        float4 v1 = *(const float4*)(s + 4);
        uint4 o;
        o.x = pack2bf(v0.x, v0.y);
        o.y = pack2bf(v0.z, v0.w);
        o.z = pack2bf(v1.x, v1.y);
        o.w = pack2bf(v1.z, v1.w);
        *(uint4*)(dst + i) = o;
    } else {
        *(uint4*)(dst + i) = *(const uint4*)((const u16*)src + i);
    }
}

// ===========================================================================
// Fused persistent kernel: 256 blocks x 1024 threads (16 waves/CU)
//  - fixed block identity (b = bid>>3, j = bid&7); XCD = j for all phases
//  - weights bf16, per-XCD slices CONTIGUOUS -> L2-resident (R7-proven)
//  - 4 phases/ts: P1 gates | P2 tgt-slice (8-way split) | P3 scores+wc | P4 out
//  - per-b 8-block barriers; layer-0 x handoff via bypass stores
// ===========================================================================
struct KP {
    const void *input, *h0, *c0, *ctx, *bi, *bhp;
    const u16 *wiB, *whB, *waiB, *waoB;
    void* out;
    const int* flag;
    int* bbars;
    u32 *hB, *hyB;
    float *tgtF, *wc_ws, *e_ws, *esum_ws;
};

#define CTXU_FLOATS 16896     // 64 rows x 264 u32 (skewed bf16 pairs)
#define SCR_FLOATS  5504      // P1: 1024+4224+256 ; P2: 512+1056 ; P3: 592 ; P4: 3201
#define SMEM_FLOATS (CTXU_FLOATS + SCR_FLOATS + 64)

template<bool F32>
__device__ void run_all(const KP& p, float* smem) {
    const int bid = blockIdx.x;
    const int tid = threadIdx.x;
    const int b  = bid >> 3;
    const int j8 = bid & 7;           // cc for P1/P4, sg for P2/P3
    const size_t XN = (size_t)Bb * Tt * Hh;
    const size_t HN = (size_t)Bb * Hh;
    u32*   ctxU = (u32*)smem;
    float* S    = smem + CTXU_FLOATS;
    float* cL   = smem + CTXU_FLOATS + SCR_FLOATS;   // 64 floats, persistent
    int*   ctr  = p.bbars + b * 64;
    int ep = 0;

    // ---- one-time: stage ctx slice (b, sg=j8) into LDS (bf16-packed, skewed)
    for (int idx = tid; idx < 8192; idx += 1024) {
        const int r = idx >> 7, q4 = (idx & 127) << 2;
        float4 v = ld4<F32>(p.ctx, ((size_t)((j8 << 6) + r) * Bb + b) * Hh + q4);
        const int w = q4 >> 1;
        const int sk = w >> 5;
        ctxU[r * 264 + w + sk]     = pack2bf(v.x, v.y);
        ctxU[r * 264 + w + 1 + sk] = pack2bf(v.z, v.w);
    }
    __syncthreads();

    for (int l = 0; l < 2; ++l) {
        const size_t wOffG  = (size_t)l * Hh * G4H;
        const size_t bOffG  = (size_t)l * G4H;
        const size_t wOffAi = (size_t)l * Hh * Hh;
        const size_t wOffAo = (size_t)l * 2 * Hh * Hh;
        const size_t offH1  = XN + (size_t)l * HN;
        const size_t offC1  = XN + 2 * HN + (size_t)l * HN;
        const size_t offAtt = XN + 4 * HN;
        const int writeAtt = l;

        for (int t = 0; t < Tt; ++t) {
            const int last = (t == Tt - 1);
            const size_t xrow = ((size_t)b * Tt + t) * Hh;

            { // ---- P1: gates -> hy, cy.  block = (b, cc): 64 cols, K=1024, 16 chunks ----
                const int cc = j8;
                float* xh  = S;                 // 1024
                float* red = S + 1024;          // [16][264]
                float* ga  = S + 1024 + 4224;   // 256
                // stage x
                if (l == 0) {
                    if (tid < 128) {
                        float4 v = ld4<F32>(p.input, xrow + (tid << 2));
                        float* d = xh + (tid << 2);
                        d[0] = v.x; d[1] = v.y; d[2] = v.z; d[3] = v.w;
                    }
                } else {
                    if (tid < 256) {
                        if constexpr (F32) {
                            float2 v = ldb2((const float*)p.out + xrow + (tid << 1));
                            xh[(tid << 1)] = v.x; xh[(tid << 1) + 1] = v.y;
                        } else {
                            u32 u = ldbu((const u32*)p.out + (xrow >> 1) + tid);
                            xh[(tid << 1)] = bflo(u); xh[(tid << 1) + 1] = bfhi(u);
                        }
                    }
                }
                // stage h
                if (t == 0) {
                    if (tid < 128) {
                        float4 v = ld4<F32>(p.h0, (size_t)b * Hh + (tid << 2));
                        float* d = xh + 512 + (tid << 2);
                        d[0] = v.x; d[1] = v.y; d[2] = v.z; d[3] = v.w;
                    }
                } else {
                    if (tid < 256) {
                        u32 u = ldbu(p.hB + b * 256 + tid);
                        xh[512 + (tid << 1)] = bflo(u); xh[512 + (tid << 1) + 1] = bfhi(u);
                    }
                }
                // zero wc / esum for this timestep
                if (cc == 0) {
                    if (tid < 512) stb(p.wc_ws + (size_t)b * Hh + tid, 0.f);
                    if (tid == 0) stb(p.esum_ws + b, 0.f);
                }
                __syncthreads();

                const int kq  = tid >> 6;       // 0..15 (K chunk of 64; <8 -> Wi)
                const int rem = tid & 63;
                const int g   = rem >> 4;       // gate 0..3
                const int j4  = rem & 15;       // 4 cols
                const u16* Wb = (kq < 8) ? p.wiB : p.whB;
                size_t wi = wOffG + ((size_t)((kq & 7) << 6)) * G4H
                          + (size_t)((g << 9) + (cc << 6) + (j4 << 2));
                const float* xr = xh + (kq << 6);    // kq*64: x then h, contiguous
                float a0 = 0.f, a1 = 0.f, a2 = 0.f, a3 = 0.f;
                #pragma unroll 8
                for (int k = 0; k < 64; ++k) {
                    float4 w = ld4<false>(Wb, wi);
                    float xv = xr[k];
                    a0 += xv * w.x; a1 += xv * w.y; a2 += xv * w.z; a3 += xv * w.w;
                    wi += G4H;
                }
                float4 rv; rv.x = a0; rv.y = a1; rv.z = a2; rv.w = a3;
                *(float4*)(red + kq * 264 + (g << 6) + (j4 << 2)) = rv;
                __syncthreads();
                if (tid < 256) {
                    float s = 0.f;
                    #pragma unroll
                    for (int q = 0; q < 16; ++q) s += red[q * 264 + tid];
                    ga[tid] = s;
                }
                __syncthreads();
                if (tid < 64) {
                    const int j = tid;
                    const int n = (cc << 6) + j;
                    float gi = ga[j]        + ldin<F32>(p.bi, bOffG + n)        + ldin<F32>(p.bhp, bOffG + n);
                    float gf = ga[64 + j]   + ldin<F32>(p.bi, bOffG + 512 + n)  + ldin<F32>(p.bhp, bOffG + 512 + n);
                    float gg = ga[128 + j]  + ldin<F32>(p.bi, bOffG + 1024 + n) + ldin<F32>(p.bhp, bOffG + 1024 + n);
                    float go = ga[192 + j]  + ldin<F32>(p.bi, bOffG + 1536 + n) + ldin<F32>(p.bhp, bOffG + 1536 + n);
                    float ig = 1.f / (1.f + __expf(-gi));
                    float fg = 1.f / (1.f + __expf(-gf));
                    float g2 = tanhf(gg);
                    float og = 1.f / (1.f + __expf(-go));
                    float cp = (t == 0) ? ldin<F32>(p.c0, (size_t)b * Hh + n) : cL[j];
                    float cy = fg * cp + ig * g2;
                    float hy = og * tanhf(cy);
                    cL[j] = cy;
                    if (last) stout<F32>(p.out, offC1 + (size_t)b * Hh + n, cy);
                    float ohy = __shfl_xor(hy, 1);
                    if (!(j & 1))
                        stbu(p.hyB + b * 256 + (cc << 5) + (j >> 1), pack2bf(hy, ohy));
                }
            }
            bbar(ctr, (++ep) << 3);

            { // ---- P2: tgt slice = hy @ Wa_in[:, sg*64..+64).  block = (b, sg) ----
                const int sg = j8;
                float* hyL = S;                 // 512
                float* red = S + 512;           // [16][66]
                if (tid < 256) {
                    u32 u = ldbu(p.hyB + b * 256 + tid);
                    hyL[(tid << 1)] = bflo(u); hyL[(tid << 1) + 1] = bfhi(u);
                }
                __syncthreads();
                const int kq = tid >> 6;        // 0..15 (32 rows each)
                const int c  = tid & 63;
                size_t wi = wOffAi + ((size_t)(kq << 5)) * Hh + (size_t)((sg << 6) + c);
                const float* hr = hyL + (kq << 5);
                float a = 0.f;
                #pragma unroll 8
                for (int k = 0; k < 32; ++k) {
                    a += hr[k] * ldin<false>(p.waiB, wi);
                    wi += Hh;
                }
                red[kq * 66 + c] = a;
                __syncthreads();
                if (tid < 64) {
                    float s = 0.f;
                    #pragma unroll
                    for (int q = 0; q < 16; ++q) s += red[q * 66 + tid];
                    float o = __shfl_xor(s, 1);
                    if (!(tid & 1))
                        stb2(p.tgtF + (size_t)b * Hh + (sg << 6) + tid, s, o);
                }
            }
            bbar(ctr, (++ep) << 3);

            { // ---- P3: R8-verbatim scores/wc; tgt loaded from tgtF.  block = (b, sg) ----
                const int sg = j8;
                float* tgtL = S;                // [8][66] skewed
                float* eL   = S + 528;          // 64
                if (tid < 256) {
                    float2 v = ldb2(p.tgtF + (size_t)b * Hh + (tid << 1));
                    const int m = tid << 1;
                    float* dst = tgtL + (m >> 6) * 66 + (m & 63);
                    dst[0] = v.x; dst[1] = v.y;
                }
                __syncthreads();
                if (tid < 512) {    // R8-verbatim score computation
                    const int r = tid >> 3, kq = tid & 7;
                    const u32* cw = ctxU + r * 264 + kq * 33;
                    const float* tp = tgtL + kq * 66;
                    float d = 0.f;
                    #pragma unroll 8
                    for (int j = 0; j < 32; ++j) {
                        u32 u = cw[j];
                        d += __uint_as_float(u << 16)         * tp[2 * j]
                           + __uint_as_float(u & 0xffff0000u) * tp[2 * j + 1];
                    }
                    d += __shfl_xor(d, 1); d += __shfl_xor(d, 2); d += __shfl_xor(d, 4);
                    if (kq == 0) {
                        float e = __expf(d);    // bounded: |score| <~ 60, safe in fp32
                        eL[r] = e;
                        stb(p.e_ws + (size_t)b * Ss + (sg << 6) + r, e);
                    }
                }
                __syncthreads();
                if (tid < 64) {
                    float w = eL[tid];
                    #pragma unroll
                    for (int o = 32; o > 0; o >>= 1) w += __shfl_xor(w, o);
                    if (tid == 0) atomicAdd(p.esum_ws + b, w);
                }
                if (tid < 512) {    // R8-verbatim wc partials
                    const int wd = tid >> 1, hodd = tid & 1;
                    const int woff = wd + (wd >> 5);
                    float acc = 0.f;
                    #pragma unroll 8
                    for (int rr = 0; rr < 64; ++rr) {
                        u32 u = ctxU[rr * 264 + woff];
                        float v = hodd ? __uint_as_float(u & 0xffff0000u) : __uint_as_float(u << 16);
                        acc += eL[rr] * v;
                    }
                    atomicAdd(p.wc_ws + (size_t)b * Hh + tid, acc);
                }
            }
            bbar(ctr, (++ep) << 3);

            { // ---- P4: h~ = tanh([wc,hy]@Wa_out).  block = (b, cc): 64 cols, 32 chunks ----
                const int cc = j8;
                float* vL   = S;                // 1024
                float* red  = S + 1024;         // [32][68]
                float* invL = S + 1024 + 2176;  // 1
                if (tid == 0) invL[0] = 1.f / ldb(p.esum_ws + b);
                if (tid < 256) {
                    float2 v = ldb2(p.wc_ws + (size_t)b * Hh + (tid << 1));
                    vL[(tid << 1)] = v.x; vL[(tid << 1) + 1] = v.y;
                    u32 u = ldbu(p.hyB + b * 256 + tid);
                    vL[512 + (tid << 1)] = bflo(u); vL[512 + (tid << 1) + 1] = bfhi(u);
                }
                __syncthreads();
                const float inv = invL[0];
                if (tid < 512) vL[tid] *= inv;  // exactly the wc half
                __syncthreads();
                const int ko = tid >> 5;        // 0..31 (32-row K chunks)
                const int jp = tid & 31;        // col pair
                const int n0 = (cc << 6) + (jp << 1);
                size_t wi = wOffAo + ((size_t)(ko << 5)) * Hh + n0;
                const float* vr = vL + (ko << 5);
                float a0 = 0.f, a1 = 0.f;
                #pragma unroll 8
                for (int k = 0; k < 32; ++k) {
                    u32 u = *(const u32*)(p.waoB + wi);
                    a0 += vr[k] * bflo(u); a1 += vr[k] * bfhi(u);
                    wi += Hh;
                }
                red[ko * 68 + (jp << 1)] = a0; red[ko * 68 + (jp << 1) + 1] = a1;
                __syncthreads();
                if (tid < 64) {
                    float s = 0.f;
                    #pragma unroll
                    for (int q = 0; q < 32; ++q) s += red[q * 68 + tid];
                    float th = tanhf(s);
                    const int n2 = (cc << 6) + tid;
                    float oth = __shfl_xor(th, 1);
                    if (l == 0) {
                        // bypass pair store: layer-1 reads this cross-XCD, coherent by construction
                        if (!(tid & 1)) stout2b<F32>(p.out, xrow + n2, th, oth);
                    } else {
                        stout<F32>(p.out, xrow + n2, th);
                    }
                    if (last) stout<F32>(p.out, offH1 + (size_t)b * Hh + n2, th);
                    if (!(tid & 1))
                        stbu(p.hB + b * 256 + (cc << 5) + (tid >> 1), pack2bf(th, oth));
                    if (writeAtt) {
                        float pv = ldb(p.e_ws + (size_t)b * Ss + n2) * inv;
                        stout<F32>(p.out, offAtt + (size_t)n2 * (Tt * Bb) + (size_t)t * Bb + b, pv);
                    }
                }
            }
            bbar(ctr, (++ep) << 3);
        }
    }
}

__global__ __launch_bounds__(1024, 1) void kmain(KP p) {
    __shared__ float smem[SMEM_FLOATS];
    if (*p.flag) run_all<true >(p, smem);
    else         run_all<false>(p, smem);
}

// ===========================================================================
// Fallback path: original per-timestep kernels (proven correct)
// ===========================================================================
template<bool F32>
__device__ __forceinline__ void gates_body(
    const void* xsrc, const void* h0, const void* c0,
    const void* Wi, const void* bi, const void* Wh, const void* bh,
    size_t wOff, size_t bOff,
    const float* h_ws, float* c_ws, float* hy_ws,
    void* out, unsigned long long offC1, int t, int writeC1)
{
    __shared__ float xh[1024];
    __shared__ float red[4][32][8];
    __shared__ float ga[4][32];

    const int b  = blockIdx.x >> 4;
    const int jc = blockIdx.x & 15;
    const int tid = threadIdx.x;

    const size_t xrow = ((size_t)b * Tt + t) * Hh;
    for (int i = tid; i < 512; i += 256) xh[i] = ldin<F32>(xsrc, xrow + i);
    if (t == 0) {
        for (int i = tid; i < 512; i += 256) xh[512 + i] = ldin<F32>(h0, (size_t)b * Hh + i);
    } else {
        for (int i = tid; i < 512; i += 256) xh[512 + i] = h_ws[b * Hh + i];
    }
    __syncthreads();

    const int jl = tid & 31;
    const int kq = tid >> 5;
    const int j  = jc * 32 + jl;
    const void* Wbase = (kq < 4) ? Wi : Wh;
    const int k0 = (kq & 3) * 128;
    const int xoff = (kq < 4) ? 0 : 512;

    float a0 = 0.f, a1 = 0.f, a2 = 0.f, a3 = 0.f;
    size_t widx = wOff + (size_t)k0 * G4H + j;
    #pragma unroll 4
    for (int k = 0; k < 128; ++k) {
        float xv = xh[xoff + k0 + k];
        a0 += xv * ldin<F32>(Wbase, widx + 0 * Hh);
        a1 += xv * ldin<F32>(Wbase, widx + 1 * Hh);
        a2 += xv * ldin<F32>(Wbase, widx + 2 * Hh);
        a3 += xv * ldin<F32>(Wbase, widx + 3 * Hh);
        widx += G4H;
    }
    red[0][jl][kq] = a0; red[1][jl][kq] = a1;
    red[2][jl][kq] = a2; red[3][jl][kq] = a3;
    __syncthreads();

    if (tid < 128) {
        int g = tid >> 5, jj = tid & 31;
        float s = 0.f;
        #pragma unroll
        for (int q = 0; q < 8; ++q) s += red[g][jj][q];
        ga[g][jj] = s;
    }
    __syncthreads();

    if (tid < 32) {
        int jj = tid;
        int n = jc * 32 + jj;
        float gi = ga[0][jj] + ldin<F32>(bi, bOff + 0 * Hh + n) + ldin<F32>(bh, bOff + 0 * Hh + n);
        float gf = ga[1][jj] + ldin<F32>(bi, bOff + 1 * Hh + n) + ldin<F32>(bh, bOff + 1 * Hh + n);
        float gg = ga[2][jj] + ldin<F32>(bi, bOff + 2 * Hh + n) + ldin<F32>(bh, bOff + 2 * Hh + n);
        float go = ga[3][jj] + ldin<F32>(bi, bOff + 3 * Hh + n) + ldin<F32>(bh, bOff + 3 * Hh + n);
        float ig = 1.f / (1.f + __expf(-gi));
        float fg = 1.f / (1.f + __expf(-gf));
        float g2 = tanhf(gg);
        float og = 1.f / (1.f + __expf(-go));
        float cp = (t == 0) ? ldin<F32>(c0, (size_t)b * Hh + n) : c_ws[b * Hh + n];
        float cy = fg * cp + ig * g2;
        float hy = og * tanhf(cy);
        c_ws[b * Hh + n]  = cy;
        hy_ws[b * Hh + n] = hy;
        if (writeC1) stout<F32>(out, offC1 + (size_t)b * Hh + n, cy);
    }
}

__global__ __launch_bounds__(256) void k_gates(
    const int* flag, const void* xsrc, const void* h0, const void* c0,
    const void* Wi, const void* bi, const void* Wh, const void* bh,
    unsigned long long wOff, unsigned long long bOff,
    const float* h_ws, float* c_ws, float* hy_ws,
    void* out, unsigned long long offC1, int t, int writeC1)
{
    if (*flag) gates_body<true >(xsrc, h0, c0, Wi, bi, Wh, bh, wOff, bOff, h_ws, c_ws, hy_ws, out, offC1, t, writeC1);
    else       gates_body<false>(xsrc, h0, c0, Wi, bi, Wh, bh, wOff, bOff, h_ws, c_ws, hy_ws, out, offC1, t, writeC1);
}

template<bool F32>
__device__ __forceinline__ void target_body(
    const float* hy_ws, const void* Wa_in, size_t wOff, float* tgt_ws)
{
    __shared__ float hyL[512];
    __shared__ float red[64][4];

    const int b  = blockIdx.x >> 3;
    const int nc = blockIdx.x & 7;
    const int tid = threadIdx.x;

    for (int i = tid; i < 512; i += 256) hyL[i] = hy_ws[b * Hh + i];
    __syncthreads();

    const int nl = tid & 63;
    const int kq = tid >> 6;
    const int n  = nc * 64 + nl;
    const int kb = kq * 128;
    float acc = 0.f;
    #pragma unroll 4
    for (int k = 0; k < 128; ++k)
        acc += hyL[kb + k] * ldin<F32>(Wa_in, wOff + (size_t)(kb + k) * Hh + n);
    red[nl][kq] = acc;
    __syncthreads();

    if (tid < 64) {
        float s = red[tid][0] + red[tid][1] + red[tid][2] + red[tid][3];
        tgt_ws[b * Hh + nc * 64 + tid] = s;
    }
}

__global__ __launch_bounds__(256) void k_target(
    const int* flag, const float* hy_ws, const void* Wa_in,
    unsigned long long wOff, float* tgt_ws)
{
    if (*flag) target_body<true >(hy_ws, Wa_in, wOff, tgt_ws);
    else       target_body<false>(hy_ws, Wa_in, wOff, tgt_ws);
}

template<bool F32>
__device__ __forceinline__ void scores_body(
    const void* ctx, const float* tgt_ws, float* sc_ws)
{
    const int w    = threadIdx.x >> 6;
    const int lane = threadIdx.x & 63;
    const int id = blockIdx.x * 4 + w;
    const int b = id & 31;
    const int s = id >> 5;

    const size_t base = ((size_t)s * Bb + b) * Hh + lane * 8;
    const float* tp = tgt_ws + (size_t)b * Hh + lane * 8;
    float d = 0.f;
    #pragma unroll
    for (int i = 0; i < 8; ++i) d += ldin<F32>(ctx, base + i) * tp[i];
    #pragma unroll
    for (int o = 32; o > 0; o >>= 1) d += __shfl_xor(d, o);
    if (lane == 0) sc_ws[b * Ss + s] = d;
}

__global__ __launch_bounds__(256) void k_scores(
    const int* flag, const void* ctx, const float* tgt_ws, float* sc_ws)
{
    if (*flag) scores_body<true >(ctx, tgt_ws, sc_ws);
    else       scores_body<false>(ctx, tgt_ws, sc_ws);
}

template<bool F32>
__device__ __forceinline__ void wc_body(
    const void* ctx, const float* sc_ws, float* wc_ws,
    void* out, unsigned long long offAtt, int t, int writeAtt)
{
    __shared__ float scL[512];
    __shared__ float red[256];

    const int b   = blockIdx.x >> 2;
    const int hc  = blockIdx.x & 3;
    const int tid = threadIdx.x;

    scL[tid]       = sc_ws[b * Ss + tid];
    scL[tid + 256] = sc_ws[b * Ss + tid + 256];
    __syncthreads();

    red[tid] = fmaxf(scL[tid], scL[tid + 256]);
    __syncthreads();
    for (int o = 128; o > 0; o >>= 1) {
        if (tid < o) red[tid] = fmaxf(red[tid], red[tid + o]);
        __syncthreads();
    }
    const float M = red[0];
    __syncthreads();

    red[tid] = __expf(scL[tid] - M) + __expf(scL[tid + 256] - M);
    __syncthreads();
    for (int o = 128; o > 0; o >>= 1) {
        if (tid < o) red[tid] += red[tid + o];
        __syncthreads();
    }
    const float inv = 1.f / red[0];
    __syncthreads();

    const int h    = hc * 128 + (tid & 127);
    const int half = tid >> 7;
    float acc = 0.f;
    const int s0 = half * 256;
    for (int s = s0; s < s0 + 256; ++s)
        acc += __expf(scL[s] - M) * ldin<F32>(ctx, ((size_t)s * Bb + b) * Hh + h);

    red[tid] = acc;
    __syncthreads();
    if (half == 0)
        wc_ws[b * Hh + h] = (red[tid] + red[tid + 128]) * inv;

    if (writeAtt && hc == 0) {
        float p0 = __expf(scL[tid] - M) * inv;
        float p1 = __expf(scL[tid + 256] - M) * inv;
        stout<F32>(out, offAtt + (size_t)tid         * (Tt * Bb) + (size_t)t * Bb + b, p0);
        stout<F32>(out, offAtt + (size_t)(tid + 256) * (Tt * Bb) + (size_t)t * Bb + b, p1);
    }
}

__global__ __launch_bounds__(256) void k_wc(
    const int* flag, const void* ctx, const float* sc_ws, float* wc_ws,
    void* out, unsigned long long offAtt, int t, int writeAtt)
{
    if (*flag) wc_body<true >(ctx, sc_ws, wc_ws, out, offAtt, t, writeAtt);
    else       wc_body<false>(ctx, sc_ws, wc_ws, out, offAtt, t, writeAtt);
}

template<bool F32>
__device__ __forceinline__ void out_body(
    const float* hy_ws, const float* wc_ws, const void* Wa_out, size_t wOff,
    float* h_ws, void* out, unsigned long long offH1, int t, int writeH1)
{
    __shared__ float vL[1024];
    __shared__ float red[32][8];

    const int b  = blockIdx.x >> 4;
    const int nc = blockIdx.x & 15;
    const int tid = threadIdx.x;

    for (int h = tid; h < 512; h += 256) {
        vL[h]       = wc_ws[b * Hh + h];
        vL[512 + h] = hy_ws[b * Hh + h];
    }
    __syncthreads();

    const int nl = tid & 31;
    const int kq = tid >> 5;
    const int n  = nc * 32 + nl;
    const int kb = kq * 128;
    float acc = 0.f;
    #pragma unroll 4
    for (int k = 0; k < 128; ++k)
        acc += vL[kb + k] * ldin<F32>(Wa_out, wOff + (size_t)(kb + k) * Hh + n);
    red[nl][kq] = acc;
    __syncthreads();

    if (tid < 32) {
        float s = 0.f;
        #pragma unroll
        for (int q = 0; q < 8; ++q) s += red[tid][q];
        float th = tanhf(s);
        int n2 = nc * 32 + tid;
        h_ws[b * Hh + n2] = th;
        stout<F32>(out, ((size_t)b * Tt + t) * Hh + n2, th);
        if (writeH1) stout<F32>(out, offH1 + (size_t)b * Hh + n2, th);
    }
}

__global__ __launch_bounds__(256) void k_out(
    const int* flag, const float* hy_ws, const float* wc_ws, const void* Wa_out,
    unsigned long long wOff, float* h_ws, void* out,
    unsigned long long offH1, int t, int writeH1)
{
    if (*flag) out_body<true >(hy_ws, wc_ws, Wa_out, wOff, h_ws, out, offH1, t, writeH1);
    else       out_body<false>(hy_ws, wc_ws, Wa_out, wOff, h_ws, out, offH1, t, writeH1);
}

// ---------------------------------------------------------------------------
extern "C" void kernel_launch(void* const* d_in, const int* in_sizes, int n_in,
                              void* d_out, int out_size, void* d_ws, size_t ws_size,
                              hipStream_t stream)
{
    const void* input  = d_in[0];
    const void* h0     = d_in[1];
    const void* c0     = d_in[2];
    const void* ctx    = d_in[3];
    const void* Wi     = d_in[4];
    const void* bi     = d_in[5];
    const void* Wh     = d_in[6];
    const void* bh     = d_in[7];
    const void* Wa_in  = d_in[8];
    const void* Wa_out = d_in[9];

    const size_t XN = (size_t)Bb * Tt * Hh;
    const size_t HN = (size_t)Bb * Hh;
    const unsigned long long offH1base = XN;
    const unsigned long long offC1base = XN + 2 * HN;
    const unsigned long long offAtt    = XN + 4 * HN;

    char* base = (char*)d_ws;
    int* flag  = (int*)base;
    int* bbars = (int*)(base + 128);                   // 32 groups x 64 ints
    float* f   = (float*)(base + 128 + 32 * 64 * 4);
    float* h_ws    = f; f += HN;                       // fallback only
    float* c_ws    = f; f += HN;                       // fallback only
    float* hy_ws   = f; f += HN;                       // fallback only
    float* tgt_ws  = f; f += HN;                       // fused: fp32 tgt exchange
    float* wc_ws   = f; f += HN;
    float* e_ws    = f; f += (size_t)Bb * Ss;
    float* sc_ws   = f; f += (size_t)Bb * Ss;          // fallback only
    float* esum_ws = f; f += 64;

    size_t off = ((size_t)((char*)f - base) + 255) & ~(size_t)255;
    u32* hB   = (u32*)(base + off); off += 32 * 256 * 4;
    u32* hyB  = (u32*)(base + off); off += 32 * 256 * 4;
    off = (off + 255) & ~(size_t)255;
    const size_t NWI  = (size_t)2 * 512 * 2048;
    const size_t NWH  = (size_t)2 * 512 * 2048;
    const size_t NWAI = (size_t)2 * 512 * 512;
    const size_t NWAO = (size_t)2 * 1024 * 512;
    u16* wiB  = (u16*)(base + off); off += NWI * 2;
    u16* whB  = (u16*)(base + off); off += NWH * 2;
    u16* waiB = (u16*)(base + off); off += NWAI * 2;
    u16* waoB = (u16*)(base + off); off += NWAO * 2;
    const int fits = (ws_size >= off) ? 1 : 0;

    k_detect<<<dim3(1), dim3(256), 0, stream>>>(ctx, flag, bbars);

    hipError_t err = hipErrorUnknown;
    if (fits) {
        k_cvt<<<dim3((unsigned)(NWI  / 2048)), dim3(256), 0, stream>>>(flag, Wi,     wiB);
        k_cvt<<<dim3((unsigned)(NWH  / 2048)), dim3(256), 0, stream>>>(flag, Wh,     whB);
        k_cvt<<<dim3((unsigned)(NWAI / 2048)), dim3(256), 0, stream>>>(flag, Wa_in,  waiB);
        k_cvt<<<dim3((unsigned)(NWAO / 2048)), dim3(256), 0, stream>>>(flag, Wa_out, waoB);

        KP hp;
        hp.input = input; hp.h0 = h0; hp.c0 = c0; hp.ctx = ctx;
        hp.bi = bi; hp.bhp = bh;
        hp.wiB = wiB; hp.whB = whB; hp.waiB = waiB; hp.waoB = waoB;
        hp.out = d_out; hp.flag = flag; hp.bbars = bbars;
        hp.hB = hB; hp.hyB = hyB;
        hp.tgtF = tgt_ws; hp.wc_ws = wc_ws; hp.e_ws = e_ws; hp.esum_ws = esum_ws;

        void* kargs[] = { &hp };
        err = hipLaunchCooperativeKernel(kmain, dim3(NBLK), dim3(1024), kargs, 0u, stream);
    }

    if (err != hipSuccess) {
        (void)hipGetLastError();   // clear error state
        // Fallback: proven per-timestep multi-kernel path
        for (int l = 0; l < 2; ++l) {
            const void* xsrc = (l == 0) ? input : (const void*)d_out;
            const unsigned long long wOffG  = (unsigned long long)l * Hh * G4H;
            const unsigned long long bOffG  = (unsigned long long)l * G4H;
            const unsigned long long wOffAi = (unsigned long long)l * Hh * Hh;
            const unsigned long long wOffAo = (unsigned long long)l * 2 * Hh * Hh;
            const unsigned long long offH1  = offH1base + (unsigned long long)l * HN;
            const unsigned long long offC1  = offC1base + (unsigned long long)l * HN;

            for (int t = 0; t < Tt; ++t) {
                const int last = (t == Tt - 1) ? 1 : 0;
                k_gates<<<dim3(512), dim3(256), 0, stream>>>(
                    flag, xsrc, h0, c0, Wi, bi, Wh, bh, wOffG, bOffG,
                    h_ws, c_ws, hy_ws, d_out, offC1, t, last);
                k_target<<<dim3(256), dim3(256), 0, stream>>>(
                    flag, hy_ws, Wa_in, wOffAi, tgt_ws);
                k_scores<<<dim3(4096), dim3(256), 0, stream>>>(
                    flag, ctx, tgt_ws, sc_ws);
                k_wc<<<dim3(128), dim3(256), 0, stream>>>(
                    flag, ctx, sc_ws, wc_ws, d_out, offAtt, t, l);
                k_out<<<dim3(512), dim3(256), 0, stream>>>(
                    flag, hy_ws, wc_ws, Wa_out, wOffAo, h_ws, d_out, offH1, t, last);
            }
        }
    }
}